// Round 11
// baseline (319.693 us; speedup 1.0000x reference)
//
#include <hip/hip_runtime.h>
#include <hip/hip_bf16.h>

#define H 4
#define DK 64
#define DM 256
#define SEN 8192
#define NG 4096
#define ETOT 262144
#define PLEN 64
#define MAXE 128

typedef unsigned short ushortT;
typedef __attribute__((ext_vector_type(8))) __bf16 bf16x8;
typedef __attribute__((ext_vector_type(8))) unsigned short us8;
typedef __attribute__((ext_vector_type(4))) unsigned short us4;
typedef __attribute__((ext_vector_type(4))) float f32x4;

#define TMS 264   // fallback tmat_b row stride
#define KVS 260   // edge k/v stage row stride (ushorts)

// ---- old bit-exact helpers (fallback kernel) ----
__device__ __forceinline__ ushortT f2bf(float f) {
    unsigned u = __float_as_uint(f);
    u += 0x7FFF + ((u >> 16) & 1);
    return (ushortT)(u >> 16);
}
__device__ __forceinline__ bf16x8 ldb8(const ushortT* p) {
    us8 v = *(const us8*)p;
    return __builtin_bit_cast(bf16x8, v);
}
__device__ __forceinline__ bf16x8 pack8(const float* f) {
    us8 v;
#pragma unroll
    for (int j = 0; j < 8; j++) v[j] = f2bf(f[j]);
    return __builtin_bit_cast(bf16x8, v);
}
// ---- fast native-cast helpers ----
__device__ __forceinline__ ushortT sbf(float f) {
    return __builtin_bit_cast(ushortT, (__bf16)f);
}
__device__ __forceinline__ __bf16 u2b(ushortT u) {
    return __builtin_bit_cast(__bf16, u);
}
__device__ __forceinline__ bf16x8 pack8f(float4 a, float4 b) {
    bf16x8 r;
    r[0] = (__bf16)a.x; r[1] = (__bf16)a.y; r[2] = (__bf16)a.z; r[3] = (__bf16)a.w;
    r[4] = (__bf16)b.x; r[5] = (__bf16)b.y; r[6] = (__bf16)b.z; r[7] = (__bf16)b.w;
    return r;
}

// -------------------- prefix scan of edge_len --------------------
__global__ __launch_bounds__(256) void scan_kernel(const int* __restrict__ edge_len,
                                                   int* __restrict__ starts) {
    __shared__ int part[256];
    const int tid = threadIdx.x;
    const int base = tid * 16;
    int loc[16];
    int s = 0;
#pragma unroll
    for (int i = 0; i < 16; i++) { loc[i] = s; s += edge_len[base + i]; }
    part[tid] = s;
    __syncthreads();
    if (tid == 0) {
        int acc = 0;
        for (int i = 0; i < 256; i++) { int t = part[i]; part[i] = acc; acc += t; }
    }
    __syncthreads();
    const int off = part[tid];
#pragma unroll
    for (int i = 0; i < 16; i++) starts[base + i] = off + loc[i];
}

// -------------------- copy q -> out --------------------
__global__ void copy_kernel(const float* __restrict__ q, float* __restrict__ out) {
    const size_t i = (size_t)blockIdx.x * blockDim.x + threadIdx.x;
    ((float4*)out)[i] = ((const float4*)q)[i];
}

// -------------------- weight prep: bf16 copies / transpose --------------------
__global__ __launch_bounds__(256) void wprep_kernel(
    const float* __restrict__ W_q, const float* __restrict__ W_k,
    const float* __restrict__ W_v, const float* __restrict__ W_out,
    ushortT* __restrict__ WQb, ushortT* __restrict__ WKTb,
    ushortT* __restrict__ WVb, ushortT* __restrict__ WOb) {
    const int idx = blockIdx.x * 256 + threadIdx.x;
    const int sel = idx >> 16;
    const int i = idx & 65535;
    if (sel == 0) {
        WQb[i] = sbf(W_q[i]);
    } else if (sel == 1) {
        const int c = i >> 8, d = i & 255;
        WKTb[i] = sbf(W_k[d * DM + c]);   // WKTb[c][d] = W_k[d][c]
    } else if (sel == 2) {
        WVb[i] = sbf(W_v[i]);
    } else {
        WOb[i] = sbf(W_out[i]);
    }
}

// -------------------- K1: QH + TMAT fused (16 groups/block, grid 256) ----------
__global__ __launch_bounds__(256) void qhtmat_kernel(
    const float* __restrict__ q, const int* __restrict__ token_ids,
    const ushortT* __restrict__ WQb, const ushortT* __restrict__ WKTb,
    ushortT* __restrict__ tmat_u) {
    __shared__ ushortT Al[16 * 264];
    __shared__ ushortT QHs[16 * 264];
    const int tid = threadIdx.x;
    const int g0 = blockIdx.x * 16;
    const int lane = tid & 63, w = tid >> 6, lq = lane & 15, lh = lane >> 4;
    {
        const int m = tid >> 4;
        const int c0 = (tid & 15) * 16;
        const int tok = token_ids[g0 + m];
        const float* qr = &q[(size_t)tok * DM + c0];
#pragma unroll
        for (int i = 0; i < 4; i++) {
            float4 v4 = *(const float4*)&qr[i * 4];
            us4 o;
            o[0] = sbf(v4.x); o[1] = sbf(v4.y); o[2] = sbf(v4.z); o[3] = sbf(v4.w);
            *(us4*)&Al[m * 264 + c0 + i * 4] = o;
        }
    }
    __syncthreads();
    {
        bf16x8 af[8];
#pragma unroll
        for (int kk = 0; kk < 8; kk++) af[kk] = ldb8(&Al[lq * 264 + kk * 32 + lh * 8]);
#pragma unroll
        for (int ntl = 0; ntl < 4; ntl++) {
            const int nt = w * 4 + ntl;
            f32x4 acc = {0.f, 0.f, 0.f, 0.f};
#pragma unroll
            for (int kk = 0; kk < 8; kk++) {
                bf16x8 bf = ldb8(&WQb[(nt * 16 + lq) * 256 + kk * 32 + lh * 8]);
                acc = __builtin_amdgcn_mfma_f32_16x16x32_bf16(af[kk], bf, acc, 0, 0, 0);
            }
#pragma unroll
            for (int r = 0; r < 4; r++)
                QHs[(lh * 4 + r) * 264 + nt * 16 + lq] = sbf(acc[r]);
        }
    }
    __syncthreads();
    for (int ab = 0; ab < 16; ab++) {
        const int a = ab >> 2, b = ab & 3;
        bf16x8 a0 = ldb8(&QHs[lq * 264 + a * 64 + lh * 8]);
        bf16x8 a1 = ldb8(&QHs[lq * 264 + a * 64 + 32 + lh * 8]);
#pragma unroll
        for (int ntl = 0; ntl < 4; ntl++) {
            const int nt = w * 4 + ntl;
            f32x4 acc = {0.f, 0.f, 0.f, 0.f};
            bf16x8 b0 = ldb8(&WKTb[(nt * 16 + lq) * 256 + b * 64 + lh * 8]);
            acc = __builtin_amdgcn_mfma_f32_16x16x32_bf16(a0, b0, acc, 0, 0, 0);
            bf16x8 b1 = ldb8(&WKTb[(nt * 16 + lq) * 256 + b * 64 + 32 + lh * 8]);
            acc = __builtin_amdgcn_mfma_f32_16x16x32_bf16(a1, b1, acc, 0, 0, 0);
#pragma unroll
            for (int r = 0; r < 4; r++)
                tmat_u[((size_t)(g0 + lh * 4 + r) * 16 + ab) * 256 + nt * 16 + lq] =
                    sbf(acc[r]);
        }
    }
}

// -------------------- K2: fused edge attention, coalesced k/v staging ----------
__global__ __launch_bounds__(256, 3) void edge_kernel(
    const float* __restrict__ k, const float* __restrict__ v,
    const int* __restrict__ edge_len, const int* __restrict__ starts,
    ushortT* __restrict__ tmat_u) {
    const int g = blockIdx.x;
    const int tid = threadIdx.x;
    const float scale = 0.125f;
    __shared__ float plog[128][17];
    __shared__ ushortT pT[16 * 136];
    __shared__ float red[16][16];
    __shared__ float mx[16];
    __shared__ ushortT kvb[64 * KVS];      // 64-row k chunks / 32-row v chunks
    const int start = starts[g];
    const int len = edge_len[g];
    const int lane = tid & 63, w = tid >> 6, lq = lane & 15, lh = lane >> 4;
    const int rg = tid >> 4, cc = tid & 15;
    const int nkc = (len + 31) >> 5;       // 1..4
    const int nmt = (len + 15) >> 4;       // 1..8
    const int col = (tid & 63) * 4;        // staging column (per-wave row-contiguous)
    const int rr = tid >> 6;               // staging row-within-quad = wave id

    // hoist tmat fragments (independent of staging; overlaps)
    bf16x8 btm[8];
#pragma unroll
    for (int cb = 0; cb < 8; cb++)
        btm[cb] = ldb8(&tmat_u[((size_t)g * 16 + lq) * 256 + cb * 32 + lh * 8]);

    // ---------- pass 1: k staged coalesced in 64-edge chunks ----------
    const int nch = (nmt + 3) >> 2;        // 1..2 chunks of 64 edges
    for (int c = 0; c < nch; c++) {
        const int base = c * 64;
        const int cnt = len - base;                    // >= 1
        const int rquads = (cnt < 64 ? cnt + 3 : 67) >> 2;  // 4-row quads to stage
#pragma unroll
        for (int i = 0; i < 16; i++) {
            if (i < rquads) {
                const int row = i * 4 + rr;            // wave reads one FULL row: 1KB contiguous
                const int gr = base + row;
                const int grc = (gr < len) ? gr : (len - 1);
                float4 v4 = *(const float4*)&k[(size_t)(start + grc) * DM + col];
                us4 o;
                o[0] = sbf(v4.x); o[1] = sbf(v4.y); o[2] = sbf(v4.z); o[3] = sbf(v4.w);
                *(us4*)&kvb[row * KVS + col] = o;
            }
        }
        __syncthreads();
        const int t = c * 4 + w;
        if (t < nmt) {
            f32x4 acc = {0.f, 0.f, 0.f, 0.f};
#pragma unroll
            for (int cb = 0; cb < 8; cb++) {
                bf16x8 ak = ldb8(&kvb[(w * 16 + lq) * KVS + cb * 32 + lh * 8]);
                acc = __builtin_amdgcn_mfma_f32_16x16x32_bf16(ak, btm[cb], acc, 0, 0, 0);
            }
#pragma unroll
            for (int r = 0; r < 4; r++) plog[t * 16 + lh * 4 + r][lq] = acc[r] * scale;
        }
        __syncthreads();
    }

    // ---------- softmax over edges (per ab = cc) ----------
    {
        float m = -3.0e38f;
        for (int e = rg; e < len; e += 16) m = fmaxf(m, plog[e][cc]);
        red[rg][cc] = m;
        __syncthreads();
        if (tid < 16) {
            float mm = red[0][tid];
            for (int i2 = 1; i2 < 16; i2++) mm = fmaxf(mm, red[i2][tid]);
            mx[tid] = mm;
        }
        __syncthreads();
        const float mm = mx[cc];
        float s = 0.f;
        for (int e = rg; e < len; e += 16) {
            float ex = __expf(plog[e][cc] - mm);
            plog[e][cc] = ex;
            s += ex;
        }
        red[rg][cc] = s;
        __syncthreads();
        if (tid < 16) {
            float ss = red[0][tid];
            for (int i2 = 1; i2 < 16; i2++) ss += red[i2][tid];
            mx[tid] = 1.0f / ss;
        }
        __syncthreads();
        const float inv = mx[cc];
        const int padlen = nkc * 32;
        for (int e = rg; e < padlen; e += 16) {
            float pv = (e < len) ? plog[e][cc] * inv : 0.f;
            pT[cc * 136 + e] = sbf(pv);
        }
    }
    __syncthreads();

    // ---------- pass 2: v staged coalesced in 32-edge chunks (rows CLAMPED) -----
    {
        f32x4 uacc[4];
#pragma unroll
        for (int nt = 0; nt < 4; nt++) uacc[nt] = {0.f, 0.f, 0.f, 0.f};
        for (int kc = 0; kc < nkc; kc++) {
            const int base = kc * 32;
#pragma unroll
            for (int i = 0; i < 8; i++) {
                const int row = i * 4 + rr;
                const int gr = base + row;
                const int grc = (gr < len) ? gr : (len - 1);   // clamp: finite garbage
                float4 v4 = *(const float4*)&v[(size_t)(start + grc) * DM + col];
                us4 o;
                o[0] = sbf(v4.x); o[1] = sbf(v4.y); o[2] = sbf(v4.z); o[3] = sbf(v4.w);
                *(us4*)&kvb[row * KVS + col] = o;
            }
            __syncthreads();
            bf16x8 ap = ldb8(&pT[lq * 136 + kc * 32 + lh * 8]);
#pragma unroll
            for (int nt = 0; nt < 4; nt++) {
                bf16x8 bv;
#pragma unroll
                for (int j = 0; j < 8; j++)
                    bv[j] = u2b(kvb[(lh * 8 + j) * KVS + w * 64 + nt * 16 + lq]);
                uacc[nt] = __builtin_amdgcn_mfma_f32_16x16x32_bf16(ap, bv, uacc[nt], 0, 0, 0);
            }
            __syncthreads();
        }
        const int c0 = w * 64;
#pragma unroll
        for (int nt = 0; nt < 4; nt++) {
#pragma unroll
            for (int r = 0; r < 4; r++) {
                const int ab = lh * 4 + r;
                tmat_u[((size_t)g * 16 + ab) * 256 + c0 + nt * 16 + lq] = sbf(uacc[nt][r]);
            }
        }
    }
}

// -------------------- K3: HID + NH fused (16 groups/block, grid 256) -----------
__global__ __launch_bounds__(256) void hidnh_kernel(
    const ushortT* __restrict__ Ub, const ushortT* __restrict__ WVb,
    const ushortT* __restrict__ WOb, const float* __restrict__ b_out,
    const int* __restrict__ token_ids, float* __restrict__ out) {
    __shared__ ushortT HIDs[16 * 264];
    const int tid = threadIdx.x;
    const int g0 = blockIdx.x * 16;
    const int lane = tid & 63, w = tid >> 6, lq = lane & 15, lh = lane >> 4;
#pragma unroll
    for (int a = 0; a < 4; a++) {
        f32x4 acc = {0.f, 0.f, 0.f, 0.f};
        for (int kk = 0; kk < 32; kk++) {
            const int kbase = kk * 32 + lh * 8;
            bf16x8 af = ldb8(&Ub[((size_t)(g0 + lq) * 16 + a * 4) * 256 + kbase]);
            bf16x8 bf = ldb8(&WVb[(size_t)((kbase >> 8) * 64 + w * 16 + lq) * 256 + (kbase & 255)]);
            acc = __builtin_amdgcn_mfma_f32_16x16x32_bf16(af, bf, acc, 0, 0, 0);
        }
#pragma unroll
        for (int r = 0; r < 4; r++)
            HIDs[(lh * 4 + r) * 264 + a * 64 + w * 16 + lq] = sbf(acc[r]);
    }
    __syncthreads();
    bf16x8 af2[8];
#pragma unroll
    for (int kk = 0; kk < 8; kk++) af2[kk] = ldb8(&HIDs[lq * 264 + kk * 32 + lh * 8]);
    int toks[4];
#pragma unroll
    for (int r = 0; r < 4; r++) toks[r] = token_ids[g0 + lh * 4 + r];
#pragma unroll
    for (int ntl = 0; ntl < 4; ntl++) {
        const int nt = w * 4 + ntl;
        f32x4 acc = {0.f, 0.f, 0.f, 0.f};
#pragma unroll
        for (int kk = 0; kk < 8; kk++) {
            bf16x8 bf = ldb8(&WOb[(nt * 16 + lq) * 256 + kk * 32 + lh * 8]);
            acc = __builtin_amdgcn_mfma_f32_16x16x32_bf16(af2[kk], bf, acc, 0, 0, 0);
        }
        const int n = nt * 16 + lq;
        const float bo = b_out[n];
#pragma unroll
        for (int r = 0; r < 4; r++)
            out[(size_t)toks[r] * DM + n] = acc[r] + bo;
    }
}

// -------------------- K4: W_agg fixup for src/tar rows --------------------
__global__ __launch_bounds__(256) void agg_kernel(
    const int* __restrict__ token_ids, const int* __restrict__ pair,
    const int* __restrict__ rev, const float* __restrict__ W_agg,
    const float* __restrict__ path_result, float* __restrict__ out) {
    __shared__ int gsrc, gtar;
    __shared__ float catS[512], catT[512];
    const int tid = threadIdx.x;
    if (tid == 0) { gsrc = -1; gtar = -1; }
    __syncthreads();
    const int rv = rev[0];
    const int src = (rv == 0) ? pair[0] : pair[1];
    const int tar = (rv == 0) ? pair[1] : pair[0];
    for (int i = tid; i < NG; i += 256) {
        const int tk = token_ids[i];
        if (tk == src) gsrc = i;
        if (tk == tar) gtar = i;
    }
    __syncthreads();
    const int gs = gsrc, gt = gtar;
    if (gs >= 0) {
        catS[tid] = out[(size_t)src * DM + tid];
        catS[256 + tid] = path_result[tid];
    }
    if (gt >= 0) {
        catT[tid] = path_result[tid];
        catT[256 + tid] = out[(size_t)tar * DM + tid];
    }
    __syncthreads();
    if (gs >= 0) {
        float acc = 0.f;
        for (int n = 0; n < 512; n += 4) {
            float4 w4 = *(const float4*)&W_agg[(size_t)tid * 512 + n];
            acc += w4.x * catS[n] + w4.y * catS[n + 1] + w4.z * catS[n + 2] + w4.w * catS[n + 3];
        }
        out[(size_t)src * DM + tid] = acc;
    }
    if (gt >= 0) {
        float acc = 0.f;
        for (int n = 0; n < 512; n += 4) {
            float4 w4 = *(const float4*)&W_agg[(size_t)tid * 512 + n];
            acc += w4.x * catT[n] + w4.y * catT[n + 1] + w4.z * catT[n + 2] + w4.w * catT[n + 3];
        }
        out[(size_t)tar * DM + tid] = acc;
    }
}

// -------------------- path attention part B: per path-row --------------------
__global__ __launch_bounds__(256) void pathB_kernel(
    const float* __restrict__ path, const float* __restrict__ q,
    const int* __restrict__ pair, const int* __restrict__ rev,
    const float* __restrict__ W_qpair, const float* __restrict__ W_pk,
    const float* __restrict__ W_pv,
    float* __restrict__ pv_ws, float* __restrict__ logits_ws) {
    __shared__ float cat[512];
    __shared__ float pq[256];
    __shared__ float prow[256];
    __shared__ float lp[256];
    const int p = blockIdx.x;
    const int tid = threadIdx.x;
    const int rv = rev[0];
    const int src = (rv == 0) ? pair[0] : pair[1];
    const int tar = (rv == 0) ? pair[1] : pair[0];
    cat[tid] = q[(size_t)src * DM + tid];
    cat[256 + tid] = q[(size_t)tar * DM + tid];
    prow[tid] = path[p * DM + tid];
    __syncthreads();
    float acc = 0.f;
    for (int c = 0; c < 512; c += 4) {
        float4 w4 = *(const float4*)&W_qpair[(size_t)tid * 512 + c];
        acc += w4.x * cat[c] + w4.y * cat[c + 1] + w4.z * cat[c + 2] + w4.w * cat[c + 3];
    }
    pq[tid] = acc;
    __syncthreads();
    float pkv = 0.f, pvv = 0.f;
    for (int c = 0; c < 256; c += 4) {
        float4 a4 = *(const float4*)&W_pk[tid * DM + c];
        float4 b4 = *(const float4*)&W_pv[tid * DM + c];
        float4 x4 = *(const float4*)&prow[c];
        pkv += a4.x * x4.x + a4.y * x4.y + a4.z * x4.z + a4.w * x4.w;
        pvv += b4.x * x4.x + b4.y * x4.y + b4.z * x4.z + b4.w * x4.w;
    }
    pv_ws[p * DM + tid] = pvv;
    lp[tid] = pq[tid] * pkv;
    __syncthreads();
    if (tid < H) {
        float s = 0.f;
        for (int d = 0; d < DK; d++) s += lp[tid * DK + d];
        logits_ws[tid * PLEN + p] = s * 0.125f;
    }
}

// -------------------- path attention part C: softmax + path_result --------------------
__global__ __launch_bounds__(256) void pathC_kernel(
    const float* __restrict__ pv_ws, const float* __restrict__ logits_ws,
    const float* __restrict__ W_out, const float* __restrict__ b_out,
    float* __restrict__ att_out, float* __restrict__ path_result) {
    __shared__ float att[256];
    __shared__ float pvals[256];
    const int tid = threadIdx.x;
    att[tid] = logits_ws[tid];
    __syncthreads();
    if (tid < H) {
        float m = -3.0e38f;
        for (int p = 0; p < PLEN; p++) m = fmaxf(m, att[tid * PLEN + p]);
        float s = 0.f;
        for (int p = 0; p < PLEN; p++) {
            float e = __expf(att[tid * PLEN + p] - m);
            att[tid * PLEN + p] = e;
            s += e;
        }
        float inv = 1.f / s;
        for (int p = 0; p < PLEN; p++) att[tid * PLEN + p] *= inv;
    }
    __syncthreads();
    att_out[tid] = att[tid];
    {
        const int h = tid >> 6;
        float a = 0.f;
        for (int p = 0; p < PLEN; p++) a += att[h * PLEN + p] * pv_ws[p * DM + tid];
        pvals[tid] = a;
    }
    __syncthreads();
    {
        float a = b_out[tid];
        for (int c = 0; c < 256; c += 4) {
            float4 w4 = *(const float4*)&W_out[tid * DM + c];
            a += w4.x * pvals[c] + w4.y * pvals[c + 1] + w4.z * pvals[c + 2] + w4.w * pvals[c + 3];
        }
        path_result[tid] = a;
    }
}

// -------------------- fallback: round-4 monolithic per-group kernel --------------------
__global__ __launch_bounds__(256, 4) void group_kernel(
    const float* __restrict__ q, const float* __restrict__ k, const float* __restrict__ v,
    const int* __restrict__ edge_len, const int* __restrict__ token_ids,
    const int* __restrict__ pair, const int* __restrict__ rev,
    const float* __restrict__ W_q,
    const float* __restrict__ W_k, const float* __restrict__ W_v,
    const float* __restrict__ W_out, const float* __restrict__ b_out,
    const float* __restrict__ W_agg,
    const int* __restrict__ starts, const float* __restrict__ path_result,
    float* __restrict__ out) {
    const int g = blockIdx.x;
    const int tid = threadIdx.x;
    const float scale = 0.125f;

    __shared__ float qrow[256];
    __shared__ float qh[256];
    __shared__ ushortT qh_b[4 * 72];
    __shared__ ushortT tmat_b[16 * TMS];
    __shared__ float plog[128][17];
    __shared__ ushortT pT[16 * 136];
    __shared__ ushortT u_b[4 * 1032];
    __shared__ float hid[256];
    __shared__ float nh[256];
    __shared__ float red[16][16];
    __shared__ float mx[16];

    const int tok = token_ids[g];
    const int start = starts[g];
    const int len = edge_len[g];

    const int lane = tid & 63;
    const int w = tid >> 6;
    const int lq = lane & 15;
    const int lh = lane >> 4;
    const int rg = tid >> 4;
    const int cc = tid & 15;

    qrow[tid] = q[(size_t)tok * DM + tid];
    __syncthreads();

    for (int i = 0; i < 16; i++) {
        const int r = i * 16 + rg;
        float acc = 0.f;
#pragma unroll
        for (int j4 = 0; j4 < 4; j4++) {
            const int c0 = j4 * 64 + cc * 4;
            float4 w4 = *(const float4*)&W_q[r * DM + c0];
            float4 x4 = *(const float4*)&qrow[c0];
            acc += w4.x * x4.x + w4.y * x4.y + w4.z * x4.z + w4.w * x4.w;
        }
#pragma unroll
        for (int off = 8; off; off >>= 1) acc += __shfl_down(acc, off, 16);
        if (cc == 0) qh[r] = acc;
    }
    __syncthreads();
    qh_b[(tid >> 6) * 72 + (tid & 63)] = f2bf(qh[tid]);
    __syncthreads();

    {
        const int arow = (lq < 3) ? lq : 3;
        bf16x8 aq0 = ldb8(&qh_b[arow * 72 + lh * 8]);
        bf16x8 aq1 = ldb8(&qh_b[arow * 72 + 32 + lh * 8]);
        for (int nt = 0; nt < 16; nt++) {
            const int c = nt * 16 + lq;
            f32x4 acc = {0.f, 0.f, 0.f, 0.f};
            float wf[8];
#pragma unroll
            for (int j = 0; j < 8; j++)
                wf[j] = W_k[(size_t)(w * 64 + lh * 8 + j) * DM + c];
            acc = __builtin_amdgcn_mfma_f32_16x16x32_bf16(aq0, pack8(wf), acc, 0, 0, 0);
#pragma unroll
            for (int j = 0; j < 8; j++)
                wf[j] = W_k[(size_t)(w * 64 + 32 + lh * 8 + j) * DM + c];
            acc = __builtin_amdgcn_mfma_f32_16x16x32_bf16(aq1, pack8(wf), acc, 0, 0, 0);
            if (lane < 16) {
#pragma unroll
                for (int r = 0; r < 4; r++)
                    tmat_b[(r * 4 + w) * TMS + nt * 16 + lq] = f2bf(acc[r]);
            }
        }
    }
    __syncthreads();

    {
        bf16x8 btm[8];
#pragma unroll
        for (int cb = 0; cb < 8; cb++)
            btm[cb] = ldb8(&tmat_b[lq * TMS + cb * 32 + lh * 8]);
        const int nmt = (len + 15) >> 4;
        for (int t = w; t < nmt; t += 4) {
            const int e = t * 16 + lq;
            const int ec = (e < len) ? e : (len - 1);
            const float* krow = &k[(size_t)(start + ec) * DM + lh * 8];
            f32x4 acc = {0.f, 0.f, 0.f, 0.f};
#pragma unroll
            for (int cb = 0; cb < 8; cb++) {
                float4 k0 = *(const float4*)&krow[cb * 32];
                float4 k1 = *(const float4*)&krow[cb * 32 + 4];
                float kf[8] = {k0.x, k0.y, k0.z, k0.w, k1.x, k1.y, k1.z, k1.w};
                acc = __builtin_amdgcn_mfma_f32_16x16x32_bf16(pack8(kf), btm[cb], acc, 0, 0, 0);
            }
#pragma unroll
            for (int r = 0; r < 4; r++) plog[t * 16 + lh * 4 + r][lq] = acc[r] * scale;
        }
    }
    __syncthreads();

    const int nkc = (len + 31) >> 5;
    {
        float m = -3.0e38f;
        for (int e = rg; e < len; e += 16) m = fmaxf(m, plog[e][cc]);
        red[rg][cc] = m;
        __syncthreads();
        if (tid < 16) {
            float mm = red[0][tid];
            for (int i2 = 1; i2 < 16; i2++) mm = fmaxf(mm, red[i2][tid]);
            mx[tid] = mm;
        }
        __syncthreads();
        const float mm = mx[cc];
        float s = 0.f;
        for (int e = rg; e < len; e += 16) {
            float ex = __expf(plog[e][cc] - mm);
            plog[e][cc] = ex;
            s += ex;
        }
        red[rg][cc] = s;
        __syncthreads();
        if (tid < 16) {
            float ss = red[0][tid];
            for (int i2 = 1; i2 < 16; i2++) ss += red[i2][tid];
            mx[tid] = 1.0f / ss;
        }
        __syncthreads();
        const float inv = mx[cc];
        const int padlen = nkc * 32;
        for (int e = rg; e < padlen; e += 16) {
            float pv = (e < len) ? plog[e][cc] * inv : 0.f;
            pT[cc * 136 + e] = f2bf(pv);
        }
    }
    __syncthreads();

    {
        f32x4 uacc[4];
#pragma unroll
        for (int nt = 0; nt < 4; nt++) uacc[nt] = {0.f, 0.f, 0.f, 0.f};
        const int c0 = w * 64;
#pragma unroll
        for (int kc = 0; kc < 4; kc++) {
            if (kc < nkc) {
                bf16x8 ap = ldb8(&pT[lq * 136 + kc * 32 + lh * 8]);
#pragma unroll
                for (int nt = 0; nt < 4; nt++) {
                    float bf[8];
#pragma unroll
                    for (int j = 0; j < 8; j++) {
                        int e = kc * 32 + lh * 8 + j;
                        int ecl = (e < len) ? e : (len - 1);
                        bf[j] = v[(size_t)(start + ecl) * DM + c0 + nt * 16 + lq];
                    }
                    uacc[nt] = __builtin_amdgcn_mfma_f32_16x16x32_bf16(ap, pack8(bf), uacc[nt], 0, 0, 0);
                }
            }
        }
#pragma unroll
        for (int nt = 0; nt < 4; nt++) {
#pragma unroll
            for (int r = 0; r < 4; r++) {
                const int row = lh * 4 + r;
                const int a = row >> 2, b = row & 3;
                u_b[a * 1032 + b * 256 + c0 + nt * 16 + lq] = f2bf(uacc[nt][r]);
            }
        }
    }
    __syncthreads();

    {
        const int arow = (lq < 3) ? lq : 3;
        f32x4 hacc = {0.f, 0.f, 0.f, 0.f};
        for (int kc = 0; kc < 32; kc++) {
            bf16x8 au = ldb8(&u_b[arow * 1032 + kc * 32 + lh * 8]);
            const int kk = kc * 32 + lh * 8;
            const float* wr = &W_v[(size_t)((kk >> 8) * 64 + w * 16 + lq) * DM + (kk & 255)];
            float4 w0 = *(const float4*)&wr[0];
            float4 w1 = *(const float4*)&wr[4];
            float wf[8] = {w0.x, w0.y, w0.z, w0.w, w1.x, w1.y, w1.z, w1.w};
            hacc = __builtin_amdgcn_mfma_f32_16x16x32_bf16(au, pack8(wf), hacc, 0, 0, 0);
        }
        if (lane < 16) {
#pragma unroll
            for (int r = 0; r < 4; r++) hid[r * 64 + w * 16 + lq] = hacc[r];
        }
    }
    __syncthreads();

    for (int i = 0; i < 16; i++) {
        const int m = i * 16 + rg;
        float acc = 0.f;
#pragma unroll
        for (int j4 = 0; j4 < 4; j4++) {
            const int c0 = j4 * 64 + cc * 4;
            float4 w4 = *(const float4*)&W_out[m * DM + c0];
            float4 h4 = *(const float4*)&hid[c0];
            acc += w4.x * h4.x + w4.y * h4.y + w4.z * h4.z + w4.w * h4.w;
        }
#pragma unroll
        for (int off = 8; off; off >>= 1) acc += __shfl_down(acc, off, 16);
        if (cc == 0) nh[m] = b_out[m] + acc;
    }
    __syncthreads();

    const int rv = rev[0];
    const int src = (rv == 0) ? pair[0] : pair[1];
    const int tar = (rv == 0) ? pair[1] : pair[0];
    float val;
    if (tok == src || tok == tar) {
        qrow[tid] = path_result[tid];
        __syncthreads();
        const float* x1 = (tok == src) ? nh : qrow;
        const float* x2 = (tok == src) ? qrow : nh;
        float acc = 0.f;
        for (int n = 0; n < 256; n += 4) {
            float4 w4 = *(const float4*)&W_agg[(size_t)tid * 512 + n];
            acc += w4.x * x1[n] + w4.y * x1[n + 1] + w4.z * x1[n + 2] + w4.w * x1[n + 3];
        }
        for (int n = 0; n < 256; n += 4) {
            float4 w4 = *(const float4*)&W_agg[(size_t)tid * 512 + 256 + n];
            acc += w4.x * x2[n] + w4.y * x2[n + 1] + w4.z * x2[n + 2] + w4.w * x2[n + 3];
        }
        val = acc;
    } else {
        val = nh[tid];
    }
    out[(size_t)tok * DM + tid] = val;
}

// -------------------- launcher --------------------
extern "C" void kernel_launch(void* const* d_in, const int* in_sizes, int n_in,
                              void* d_out, int out_size, void* d_ws, size_t ws_size,
                              hipStream_t stream) {
    const float* path    = (const float*)d_in[0];
    const float* q       = (const float*)d_in[2];
    const float* k       = (const float*)d_in[3];
    const float* v       = (const float*)d_in[4];
    const int*   edge_len  = (const int*)d_in[6];
    const int*   token_ids = (const int*)d_in[7];
    const int*   pair      = (const int*)d_in[8];
    const int*   rev       = (const int*)d_in[9];
    const float* W_qpair = (const float*)d_in[10];
    const float* W_pk    = (const float*)d_in[11];
    const float* W_pv    = (const float*)d_in[12];
    const float* W_q     = (const float*)d_in[13];
    const float* W_k     = (const float*)d_in[14];
    const float* W_v     = (const float*)d_in[15];
    const float* W_out   = (const float*)d_in[16];
    const float* b_out   = (const float*)d_in[17];
    const float* W_agg   = (const float*)d_in[18];
    float* out = (float*)d_out;

    char* base = (char*)d_ws;
    int*    starts      = (int*)(base + 0);              // 16 KB
    float*  path_result = (float*)(base + 16384);        // 1 KB
    float*  pv_ws       = (float*)(base + 17408);        // 64 KB
    float*  logits_ws   = (float*)(base + 82944);        // 1 KB
    ushortT* WQb        = (ushortT*)(base + 83968);      // 128 KB
    ushortT* WKTb       = (ushortT*)(base + 215040);     // 128 KB
    ushortT* WVb        = (ushortT*)(base + 346112);     // 128 KB
    ushortT* WOb        = (ushortT*)(base + 477184);     // 128 KB
    ushortT* tmat_u     = (ushortT*)(base + 608256);     // 32 MB
    const size_t NEED = 608256 + 33554432;

    copy_kernel<<<dim3(2048), dim3(256), 0, stream>>>(q, out);
    scan_kernel<<<dim3(1), dim3(256), 0, stream>>>(edge_len, starts);
    pathB_kernel<<<dim3(PLEN), dim3(256), 0, stream>>>(path, q, pair, rev, W_qpair, W_pk,
                                                       W_pv, pv_ws, logits_ws);
    pathC_kernel<<<dim3(1), dim3(256), 0, stream>>>(pv_ws, logits_ws, W_out, b_out,
                                                    out + (size_t)SEN * DM, path_result);

    if (ws_size >= NEED) {
        wprep_kernel<<<dim3(1024), dim3(256), 0, stream>>>(W_q, W_k, W_v, W_out,
                                                           WQb, WKTb, WVb, WOb);
        qhtmat_kernel<<<dim3(256), dim3(256), 0, stream>>>(q, token_ids, WQb, WKTb, tmat_u);
        edge_kernel<<<dim3(NG), dim3(256), 0, stream>>>(k, v, edge_len, starts, tmat_u);
        hidnh_kernel<<<dim3(256), dim3(256), 0, stream>>>(tmat_u, WVb, WOb, b_out,
                                                          token_ids, out);
        agg_kernel<<<dim3(1), dim3(256), 0, stream>>>(token_ids, pair, rev, W_agg,
                                                      path_result, out);
    } else {
        group_kernel<<<dim3(NG), dim3(256), 0, stream>>>(q, k, v, edge_len, token_ids, pair,
                                                         rev, W_q, W_k, W_v, W_out, b_out,
                                                         W_agg, starts, path_result, out);
    }
}

// Round 12
// 301.358 us; speedup vs baseline: 1.0608x; 1.0608x over previous
//
#include <hip/hip_runtime.h>
#include <hip/hip_bf16.h>

#define H 4
#define DK 64
#define DM 256
#define SEN 8192
#define NG 4096
#define ETOT 262144
#define PLEN 64
#define MAXE 128

typedef unsigned short ushortT;
typedef __attribute__((ext_vector_type(8))) __bf16 bf16x8;
typedef __attribute__((ext_vector_type(8))) unsigned short us8;
typedef __attribute__((ext_vector_type(4))) unsigned short us4;
typedef __attribute__((ext_vector_type(4))) float f32x4;

#define TMS 264   // fallback tmat_b row stride
#define KVS 260   // edge k/v stage row stride (ushorts)

// ---- old bit-exact helpers (fallback kernel) ----
__device__ __forceinline__ ushortT f2bf(float f) {
    unsigned u = __float_as_uint(f);
    u += 0x7FFF + ((u >> 16) & 1);
    return (ushortT)(u >> 16);
}
__device__ __forceinline__ bf16x8 ldb8(const ushortT* p) {
    us8 v = *(const us8*)p;
    return __builtin_bit_cast(bf16x8, v);
}
__device__ __forceinline__ bf16x8 pack8(const float* f) {
    us8 v;
#pragma unroll
    for (int j = 0; j < 8; j++) v[j] = f2bf(f[j]);
    return __builtin_bit_cast(bf16x8, v);
}
// ---- fast native-cast helpers ----
__device__ __forceinline__ ushortT sbf(float f) {
    return __builtin_bit_cast(ushortT, (__bf16)f);
}
__device__ __forceinline__ __bf16 u2b(ushortT u) {
    return __builtin_bit_cast(__bf16, u);
}
__device__ __forceinline__ bf16x8 pack8f(float4 a, float4 b) {
    bf16x8 r;
    r[0] = (__bf16)a.x; r[1] = (__bf16)a.y; r[2] = (__bf16)a.z; r[3] = (__bf16)a.w;
    r[4] = (__bf16)b.x; r[5] = (__bf16)b.y; r[6] = (__bf16)b.z; r[7] = (__bf16)b.w;
    return r;
}

// ==================== FAST PATH: 4 launches ====================

// -------------------- L1: prep = copy ∥ wprep ∥ scan ∥ pathB --------------------
__global__ __launch_bounds__(256) void prep_kernel(
    const float* __restrict__ q, float* __restrict__ out,
    const int* __restrict__ edge_len, int* __restrict__ starts,
    const float* __restrict__ path, const int* __restrict__ pair,
    const int* __restrict__ rev, const float* __restrict__ W_qpair,
    const float* __restrict__ W_pk, const float* __restrict__ W_pv,
    float* __restrict__ pv_ws, float* __restrict__ logits_ws,
    const float* __restrict__ W_q, const float* __restrict__ W_k,
    const float* __restrict__ W_v, const float* __restrict__ W_out,
    ushortT* __restrict__ WQb, ushortT* __restrict__ WKTb,
    ushortT* __restrict__ WVb, ushortT* __restrict__ WOb) {
    __shared__ int part[256];
    __shared__ float cat[512];
    __shared__ float pq[256];
    __shared__ float prow[256];
    __shared__ float lp[256];
    const int b = blockIdx.x;
    const int tid = threadIdx.x;
    if (b < 2048) {                       // ---- copy q -> out ----
        const size_t i = (size_t)b * 256 + tid;
        ((float4*)out)[i] = ((const float4*)q)[i];
    } else if (b < 3072) {                // ---- weight prep ----
        const int idx = (b - 2048) * 256 + tid;
        const int sel = idx >> 16;
        const int i = idx & 65535;
        if (sel == 0) {
            WQb[i] = sbf(W_q[i]);
        } else if (sel == 1) {
            const int c = i >> 8, d = i & 255;
            WKTb[i] = sbf(W_k[d * DM + c]);
        } else if (sel == 2) {
            WVb[i] = sbf(W_v[i]);
        } else {
            WOb[i] = sbf(W_out[i]);
        }
    } else if (b == 3072) {               // ---- prefix scan ----
        const int base = tid * 16;
        int loc[16];
        int s = 0;
#pragma unroll
        for (int i = 0; i < 16; i++) { loc[i] = s; s += edge_len[base + i]; }
        part[tid] = s;
        __syncthreads();
        if (tid == 0) {
            int acc = 0;
            for (int i = 0; i < 256; i++) { int t = part[i]; part[i] = acc; acc += t; }
        }
        __syncthreads();
        const int off = part[tid];
#pragma unroll
        for (int i = 0; i < 16; i++) starts[base + i] = off + loc[i];
    } else {                              // ---- pathB, p = b - 3073 ----
        const int p = b - 3073;
        const int rv = rev[0];
        const int src = (rv == 0) ? pair[0] : pair[1];
        const int tar = (rv == 0) ? pair[1] : pair[0];
        cat[tid] = q[(size_t)src * DM + tid];
        cat[256 + tid] = q[(size_t)tar * DM + tid];
        prow[tid] = path[p * DM + tid];
        __syncthreads();
        float acc = 0.f;
        for (int c = 0; c < 512; c += 4) {
            float4 w4 = *(const float4*)&W_qpair[(size_t)tid * 512 + c];
            acc += w4.x * cat[c] + w4.y * cat[c + 1] + w4.z * cat[c + 2] + w4.w * cat[c + 3];
        }
        pq[tid] = acc;
        __syncthreads();
        float pkv = 0.f, pvv = 0.f;
        for (int c = 0; c < 256; c += 4) {
            float4 a4 = *(const float4*)&W_pk[tid * DM + c];
            float4 b4 = *(const float4*)&W_pv[tid * DM + c];
            float4 x4 = *(const float4*)&prow[c];
            pkv += a4.x * x4.x + a4.y * x4.y + a4.z * x4.z + a4.w * x4.w;
            pvv += b4.x * x4.x + b4.y * x4.y + b4.z * x4.z + b4.w * x4.w;
        }
        pv_ws[p * DM + tid] = pvv;
        lp[tid] = pq[tid] * pkv;
        __syncthreads();
        if (tid < H) {
            float s = 0.f;
            for (int d = 0; d < DK; d++) s += lp[tid * DK + d];
            logits_ws[tid * PLEN + p] = s * 0.125f;
        }
    }
}

// -------------------- L2: qhtmat (b<256) ∥ pathC (b==256) --------------------
__global__ __launch_bounds__(256) void qhtmatC_kernel(
    const float* __restrict__ q, const int* __restrict__ token_ids,
    const ushortT* __restrict__ WQb, const ushortT* __restrict__ WKTb,
    ushortT* __restrict__ tmat_u,
    const float* __restrict__ pv_ws, const float* __restrict__ logits_ws,
    const float* __restrict__ W_out, const float* __restrict__ b_out,
    float* __restrict__ att_out, float* __restrict__ path_result) {
    __shared__ ushortT Al[16 * 264];
    __shared__ ushortT QHs[16 * 264];
    __shared__ float att[256];
    __shared__ float pvals[256];
    const int tid = threadIdx.x;
    if (blockIdx.x == 256) {              // ---- pathC ----
        att[tid] = logits_ws[tid];
        __syncthreads();
        if (tid < H) {
            float m = -3.0e38f;
            for (int p = 0; p < PLEN; p++) m = fmaxf(m, att[tid * PLEN + p]);
            float s = 0.f;
            for (int p = 0; p < PLEN; p++) {
                float e = __expf(att[tid * PLEN + p] - m);
                att[tid * PLEN + p] = e;
                s += e;
            }
            float inv = 1.f / s;
            for (int p = 0; p < PLEN; p++) att[tid * PLEN + p] *= inv;
        }
        __syncthreads();
        att_out[tid] = att[tid];
        {
            const int h = tid >> 6;
            float a = 0.f;
            for (int p = 0; p < PLEN; p++) a += att[h * PLEN + p] * pv_ws[p * DM + tid];
            pvals[tid] = a;
        }
        __syncthreads();
        {
            float a = b_out[tid];
            for (int c = 0; c < 256; c += 4) {
                float4 w4 = *(const float4*)&W_out[tid * DM + c];
                a += w4.x * pvals[c] + w4.y * pvals[c + 1] + w4.z * pvals[c + 2] + w4.w * pvals[c + 3];
            }
            path_result[tid] = a;
        }
        return;
    }
    // ---- qhtmat, 16 groups/block ----
    const int g0 = blockIdx.x * 16;
    const int lane = tid & 63, w = tid >> 6, lq = lane & 15, lh = lane >> 4;
    {
        const int m = tid >> 4;
        const int c0 = (tid & 15) * 16;
        const int tok = token_ids[g0 + m];
        const float* qr = &q[(size_t)tok * DM + c0];
#pragma unroll
        for (int i = 0; i < 4; i++) {
            float4 v4 = *(const float4*)&qr[i * 4];
            us4 o;
            o[0] = sbf(v4.x); o[1] = sbf(v4.y); o[2] = sbf(v4.z); o[3] = sbf(v4.w);
            *(us4*)&Al[m * 264 + c0 + i * 4] = o;
        }
    }
    __syncthreads();
    {
        bf16x8 af[8];
#pragma unroll
        for (int kk = 0; kk < 8; kk++) af[kk] = ldb8(&Al[lq * 264 + kk * 32 + lh * 8]);
#pragma unroll
        for (int ntl = 0; ntl < 4; ntl++) {
            const int nt = w * 4 + ntl;
            f32x4 acc = {0.f, 0.f, 0.f, 0.f};
#pragma unroll
            for (int kk = 0; kk < 8; kk++) {
                bf16x8 bf = ldb8(&WQb[(nt * 16 + lq) * 256 + kk * 32 + lh * 8]);
                acc = __builtin_amdgcn_mfma_f32_16x16x32_bf16(af[kk], bf, acc, 0, 0, 0);
            }
#pragma unroll
            for (int r = 0; r < 4; r++)
                QHs[(lh * 4 + r) * 264 + nt * 16 + lq] = sbf(acc[r]);
        }
    }
    __syncthreads();
    for (int ab = 0; ab < 16; ab++) {
        const int a = ab >> 2, bb = ab & 3;
        bf16x8 a0 = ldb8(&QHs[lq * 264 + a * 64 + lh * 8]);
        bf16x8 a1 = ldb8(&QHs[lq * 264 + a * 64 + 32 + lh * 8]);
#pragma unroll
        for (int ntl = 0; ntl < 4; ntl++) {
            const int nt = w * 4 + ntl;
            f32x4 acc = {0.f, 0.f, 0.f, 0.f};
            bf16x8 b0 = ldb8(&WKTb[(nt * 16 + lq) * 256 + bb * 64 + lh * 8]);
            acc = __builtin_amdgcn_mfma_f32_16x16x32_bf16(a0, b0, acc, 0, 0, 0);
            bf16x8 b1 = ldb8(&WKTb[(nt * 16 + lq) * 256 + bb * 64 + 32 + lh * 8]);
            acc = __builtin_amdgcn_mfma_f32_16x16x32_bf16(a1, b1, acc, 0, 0, 0);
#pragma unroll
            for (int r = 0; r < 4; r++)
                tmat_u[((size_t)(g0 + lh * 4 + r) * 16 + ab) * 256 + nt * 16 + lq] =
                    sbf(acc[r]);
        }
    }
}

// -------------------- L3: edge attention (UNCHANGED from round 11) -------------
__global__ __launch_bounds__(256, 3) void edge_kernel(
    const float* __restrict__ k, const float* __restrict__ v,
    const int* __restrict__ edge_len, const int* __restrict__ starts,
    ushortT* __restrict__ tmat_u) {
    const int g = blockIdx.x;
    const int tid = threadIdx.x;
    const float scale = 0.125f;
    __shared__ float plog[128][17];
    __shared__ ushortT pT[16 * 136];
    __shared__ float red[16][16];
    __shared__ float mx[16];
    __shared__ ushortT kvb[64 * KVS];
    const int start = starts[g];
    const int len = edge_len[g];
    const int lane = tid & 63, w = tid >> 6, lq = lane & 15, lh = lane >> 4;
    const int rg = tid >> 4, cc = tid & 15;
    const int nkc = (len + 31) >> 5;
    const int nmt = (len + 15) >> 4;
    const int col = (tid & 63) * 4;
    const int rr = tid >> 6;

    bf16x8 btm[8];
#pragma unroll
    for (int cb = 0; cb < 8; cb++)
        btm[cb] = ldb8(&tmat_u[((size_t)g * 16 + lq) * 256 + cb * 32 + lh * 8]);

    const int nch = (nmt + 3) >> 2;
    for (int c = 0; c < nch; c++) {
        const int base = c * 64;
        const int cnt = len - base;
        const int rquads = (cnt < 64 ? cnt + 3 : 67) >> 2;
#pragma unroll
        for (int i = 0; i < 16; i++) {
            if (i < rquads) {
                const int row = i * 4 + rr;
                const int gr = base + row;
                const int grc = (gr < len) ? gr : (len - 1);
                float4 v4 = *(const float4*)&k[(size_t)(start + grc) * DM + col];
                us4 o;
                o[0] = sbf(v4.x); o[1] = sbf(v4.y); o[2] = sbf(v4.z); o[3] = sbf(v4.w);
                *(us4*)&kvb[row * KVS + col] = o;
            }
        }
        __syncthreads();
        const int t = c * 4 + w;
        if (t < nmt) {
            f32x4 acc = {0.f, 0.f, 0.f, 0.f};
#pragma unroll
            for (int cb = 0; cb < 8; cb++) {
                bf16x8 ak = ldb8(&kvb[(w * 16 + lq) * KVS + cb * 32 + lh * 8]);
                acc = __builtin_amdgcn_mfma_f32_16x16x32_bf16(ak, btm[cb], acc, 0, 0, 0);
            }
#pragma unroll
            for (int r = 0; r < 4; r++) plog[t * 16 + lh * 4 + r][lq] = acc[r] * scale;
        }
        __syncthreads();
    }

    {
        float m = -3.0e38f;
        for (int e = rg; e < len; e += 16) m = fmaxf(m, plog[e][cc]);
        red[rg][cc] = m;
        __syncthreads();
        if (tid < 16) {
            float mm = red[0][tid];
            for (int i2 = 1; i2 < 16; i2++) mm = fmaxf(mm, red[i2][tid]);
            mx[tid] = mm;
        }
        __syncthreads();
        const float mm = mx[cc];
        float s = 0.f;
        for (int e = rg; e < len; e += 16) {
            float ex = __expf(plog[e][cc] - mm);
            plog[e][cc] = ex;
            s += ex;
        }
        red[rg][cc] = s;
        __syncthreads();
        if (tid < 16) {
            float ss = red[0][tid];
            for (int i2 = 1; i2 < 16; i2++) ss += red[i2][tid];
            mx[tid] = 1.0f / ss;
        }
        __syncthreads();
        const float inv = mx[cc];
        const int padlen = nkc * 32;
        for (int e = rg; e < padlen; e += 16) {
            float pv = (e < len) ? plog[e][cc] * inv : 0.f;
            pT[cc * 136 + e] = sbf(pv);
        }
    }
    __syncthreads();

    {
        f32x4 uacc[4];
#pragma unroll
        for (int nt = 0; nt < 4; nt++) uacc[nt] = {0.f, 0.f, 0.f, 0.f};
        for (int kc = 0; kc < nkc; kc++) {
            const int base = kc * 32;
#pragma unroll
            for (int i = 0; i < 8; i++) {
                const int row = i * 4 + rr;
                const int gr = base + row;
                const int grc = (gr < len) ? gr : (len - 1);
                float4 v4 = *(const float4*)&v[(size_t)(start + grc) * DM + col];
                us4 o;
                o[0] = sbf(v4.x); o[1] = sbf(v4.y); o[2] = sbf(v4.z); o[3] = sbf(v4.w);
                *(us4*)&kvb[row * KVS + col] = o;
            }
            __syncthreads();
            bf16x8 ap = ldb8(&pT[lq * 136 + kc * 32 + lh * 8]);
#pragma unroll
            for (int nt = 0; nt < 4; nt++) {
                bf16x8 bv;
#pragma unroll
                for (int j = 0; j < 8; j++)
                    bv[j] = u2b(kvb[(lh * 8 + j) * KVS + w * 64 + nt * 16 + lq]);
                uacc[nt] = __builtin_amdgcn_mfma_f32_16x16x32_bf16(ap, bv, uacc[nt], 0, 0, 0);
            }
            __syncthreads();
        }
        const int c0 = w * 64;
#pragma unroll
        for (int nt = 0; nt < 4; nt++) {
#pragma unroll
            for (int r = 0; r < 4; r++) {
                const int ab = lh * 4 + r;
                tmat_u[((size_t)g * 16 + ab) * 256 + c0 + nt * 16 + lq] = sbf(uacc[nt][r]);
            }
        }
    }
}

// -------------------- L4: HID + NH + inline agg fixup --------------------
__global__ __launch_bounds__(256) void hidnhagg_kernel(
    const ushortT* __restrict__ Ub, const ushortT* __restrict__ WVb,
    const ushortT* __restrict__ WOb, const float* __restrict__ b_out,
    const int* __restrict__ token_ids, const int* __restrict__ pair,
    const int* __restrict__ rev, const float* __restrict__ W_agg,
    const float* __restrict__ path_result, float* __restrict__ out) {
    __shared__ ushortT HIDs[16 * 264];
    __shared__ float nhs[2][260];
    __shared__ float prb[256];
    __shared__ int flagrow[2];
    const int tid = threadIdx.x;
    const int g0 = blockIdx.x * 16;
    const int lane = tid & 63, w = tid >> 6, lq = lane & 15, lh = lane >> 4;
    if (tid < 2) flagrow[tid] = -1;
    prb[tid] = path_result[tid];
#pragma unroll
    for (int a = 0; a < 4; a++) {
        f32x4 acc = {0.f, 0.f, 0.f, 0.f};
        for (int kk = 0; kk < 32; kk++) {
            const int kbase = kk * 32 + lh * 8;
            bf16x8 af = ldb8(&Ub[((size_t)(g0 + lq) * 16 + a * 4) * 256 + kbase]);
            bf16x8 bf = ldb8(&WVb[(size_t)((kbase >> 8) * 64 + w * 16 + lq) * 256 + (kbase & 255)]);
            acc = __builtin_amdgcn_mfma_f32_16x16x32_bf16(af, bf, acc, 0, 0, 0);
        }
#pragma unroll
        for (int r = 0; r < 4; r++)
            HIDs[(lh * 4 + r) * 264 + a * 64 + w * 16 + lq] = sbf(acc[r]);
    }
    __syncthreads();
    bf16x8 af2[8];
#pragma unroll
    for (int kk = 0; kk < 8; kk++) af2[kk] = ldb8(&HIDs[lq * 264 + kk * 32 + lh * 8]);
    const int rv = rev[0];
    const int src = (rv == 0) ? pair[0] : pair[1];
    const int tar = (rv == 0) ? pair[1] : pair[0];
    int toks[4];
#pragma unroll
    for (int r = 0; r < 4; r++) {
        toks[r] = token_ids[g0 + lh * 4 + r];
        if (toks[r] == src) flagrow[0] = lh * 4 + r;
        else if (toks[r] == tar) flagrow[1] = lh * 4 + r;
    }
#pragma unroll
    for (int ntl = 0; ntl < 4; ntl++) {
        const int nt = w * 4 + ntl;
        f32x4 acc = {0.f, 0.f, 0.f, 0.f};
#pragma unroll
        for (int kk = 0; kk < 8; kk++) {
            bf16x8 bf = ldb8(&WOb[(nt * 16 + lq) * 256 + kk * 32 + lh * 8]);
            acc = __builtin_amdgcn_mfma_f32_16x16x32_bf16(af2[kk], bf, acc, 0, 0, 0);
        }
        const int n = nt * 16 + lq;
        const float bo = b_out[n];
#pragma unroll
        for (int r = 0; r < 4; r++) {
            const float val = acc[r] + bo;
            if (toks[r] == src) nhs[0][n] = val;
            else if (toks[r] == tar) nhs[1][n] = val;
            else out[(size_t)toks[r] * DM + n] = val;
        }
    }
    __syncthreads();
#pragma unroll
    for (int s = 0; s < 2; s++) {
        if (flagrow[s] >= 0) {
            const float* x1 = (s == 0) ? nhs[0] : prb;
            const float* x2 = (s == 0) ? prb : nhs[1];
            float acc = 0.f;
            for (int n = 0; n < 256; n += 4) {
                float4 w4 = *(const float4*)&W_agg[(size_t)tid * 512 + n];
                acc += w4.x * x1[n] + w4.y * x1[n + 1] + w4.z * x1[n + 2] + w4.w * x1[n + 3];
            }
            for (int n = 0; n < 256; n += 4) {
                float4 w4 = *(const float4*)&W_agg[(size_t)tid * 512 + 256 + n];
                acc += w4.x * x2[n] + w4.y * x2[n + 1] + w4.z * x2[n + 2] + w4.w * x2[n + 3];
            }
            out[(size_t)((s == 0) ? src : tar) * DM + tid] = acc;
        }
    }
}

// ==================== FALLBACK PATH (ws too small) ====================

__global__ __launch_bounds__(256) void scan_kernel(const int* __restrict__ edge_len,
                                                   int* __restrict__ starts) {
    __shared__ int part[256];
    const int tid = threadIdx.x;
    const int base = tid * 16;
    int loc[16];
    int s = 0;
#pragma unroll
    for (int i = 0; i < 16; i++) { loc[i] = s; s += edge_len[base + i]; }
    part[tid] = s;
    __syncthreads();
    if (tid == 0) {
        int acc = 0;
        for (int i = 0; i < 256; i++) { int t = part[i]; part[i] = acc; acc += t; }
    }
    __syncthreads();
    const int off = part[tid];
#pragma unroll
    for (int i = 0; i < 16; i++) starts[base + i] = off + loc[i];
}

__global__ void copy_kernel(const float* __restrict__ q, float* __restrict__ out) {
    const size_t i = (size_t)blockIdx.x * blockDim.x + threadIdx.x;
    ((float4*)out)[i] = ((const float4*)q)[i];
}

__global__ __launch_bounds__(256) void pathB_kernel(
    const float* __restrict__ path, const float* __restrict__ q,
    const int* __restrict__ pair, const int* __restrict__ rev,
    const float* __restrict__ W_qpair, const float* __restrict__ W_pk,
    const float* __restrict__ W_pv,
    float* __restrict__ pv_ws, float* __restrict__ logits_ws) {
    __shared__ float cat[512];
    __shared__ float pq[256];
    __shared__ float prow[256];
    __shared__ float lp[256];
    const int p = blockIdx.x;
    const int tid = threadIdx.x;
    const int rv = rev[0];
    const int src = (rv == 0) ? pair[0] : pair[1];
    const int tar = (rv == 0) ? pair[1] : pair[0];
    cat[tid] = q[(size_t)src * DM + tid];
    cat[256 + tid] = q[(size_t)tar * DM + tid];
    prow[tid] = path[p * DM + tid];
    __syncthreads();
    float acc = 0.f;
    for (int c = 0; c < 512; c += 4) {
        float4 w4 = *(const float4*)&W_qpair[(size_t)tid * 512 + c];
        acc += w4.x * cat[c] + w4.y * cat[c + 1] + w4.z * cat[c + 2] + w4.w * cat[c + 3];
    }
    pq[tid] = acc;
    __syncthreads();
    float pkv = 0.f, pvv = 0.f;
    for (int c = 0; c < 256; c += 4) {
        float4 a4 = *(const float4*)&W_pk[tid * DM + c];
        float4 b4 = *(const float4*)&W_pv[tid * DM + c];
        float4 x4 = *(const float4*)&prow[c];
        pkv += a4.x * x4.x + a4.y * x4.y + a4.z * x4.z + a4.w * x4.w;
        pvv += b4.x * x4.x + b4.y * x4.y + b4.z * x4.z + b4.w * x4.w;
    }
    pv_ws[p * DM + tid] = pvv;
    lp[tid] = pq[tid] * pkv;
    __syncthreads();
    if (tid < H) {
        float s = 0.f;
        for (int d = 0; d < DK; d++) s += lp[tid * DK + d];
        logits_ws[tid * PLEN + p] = s * 0.125f;
    }
}

__global__ __launch_bounds__(256) void pathC_kernel(
    const float* __restrict__ pv_ws, const float* __restrict__ logits_ws,
    const float* __restrict__ W_out, const float* __restrict__ b_out,
    float* __restrict__ att_out, float* __restrict__ path_result) {
    __shared__ float att[256];
    __shared__ float pvals[256];
    const int tid = threadIdx.x;
    att[tid] = logits_ws[tid];
    __syncthreads();
    if (tid < H) {
        float m = -3.0e38f;
        for (int p = 0; p < PLEN; p++) m = fmaxf(m, att[tid * PLEN + p]);
        float s = 0.f;
        for (int p = 0; p < PLEN; p++) {
            float e = __expf(att[tid * PLEN + p] - m);
            att[tid * PLEN + p] = e;
            s += e;
        }
        float inv = 1.f / s;
        for (int p = 0; p < PLEN; p++) att[tid * PLEN + p] *= inv;
    }
    __syncthreads();
    att_out[tid] = att[tid];
    {
        const int h = tid >> 6;
        float a = 0.f;
        for (int p = 0; p < PLEN; p++) a += att[h * PLEN + p] * pv_ws[p * DM + tid];
        pvals[tid] = a;
    }
    __syncthreads();
    {
        float a = b_out[tid];
        for (int c = 0; c < 256; c += 4) {
            float4 w4 = *(const float4*)&W_out[tid * DM + c];
            a += w4.x * pvals[c] + w4.y * pvals[c + 1] + w4.z * pvals[c + 2] + w4.w * pvals[c + 3];
        }
        path_result[tid] = a;
    }
}

__global__ __launch_bounds__(256, 4) void group_kernel(
    const float* __restrict__ q, const float* __restrict__ k, const float* __restrict__ v,
    const int* __restrict__ edge_len, const int* __restrict__ token_ids,
    const int* __restrict__ pair, const int* __restrict__ rev,
    const float* __restrict__ W_q,
    const float* __restrict__ W_k, const float* __restrict__ W_v,
    const float* __restrict__ W_out, const float* __restrict__ b_out,
    const float* __restrict__ W_agg,
    const int* __restrict__ starts, const float* __restrict__ path_result,
    float* __restrict__ out) {
    const int g = blockIdx.x;
    const int tid = threadIdx.x;
    const float scale = 0.125f;

    __shared__ float qrow[256];
    __shared__ float qh[256];
    __shared__ ushortT qh_b[4 * 72];
    __shared__ ushortT tmat_b[16 * TMS];
    __shared__ float plog[128][17];
    __shared__ ushortT pT[16 * 136];
    __shared__ ushortT u_b[4 * 1032];
    __shared__ float hid[256];
    __shared__ float nh[256];
    __shared__ float red[16][16];
    __shared__ float mx[16];

    const int tok = token_ids[g];
    const int start = starts[g];
    const int len = edge_len[g];

    const int lane = tid & 63;
    const int w = tid >> 6;
    const int lq = lane & 15;
    const int lh = lane >> 4;
    const int rg = tid >> 4;
    const int cc = tid & 15;

    qrow[tid] = q[(size_t)tok * DM + tid];
    __syncthreads();

    for (int i = 0; i < 16; i++) {
        const int r = i * 16 + rg;
        float acc = 0.f;
#pragma unroll
        for (int j4 = 0; j4 < 4; j4++) {
            const int c0 = j4 * 64 + cc * 4;
            float4 w4 = *(const float4*)&W_q[r * DM + c0];
            float4 x4 = *(const float4*)&qrow[c0];
            acc += w4.x * x4.x + w4.y * x4.y + w4.z * x4.z + w4.w * x4.w;
        }
#pragma unroll
        for (int off = 8; off; off >>= 1) acc += __shfl_down(acc, off, 16);
        if (cc == 0) qh[r] = acc;
    }
    __syncthreads();
    qh_b[(tid >> 6) * 72 + (tid & 63)] = f2bf(qh[tid]);
    __syncthreads();

    {
        const int arow = (lq < 3) ? lq : 3;
        bf16x8 aq0 = ldb8(&qh_b[arow * 72 + lh * 8]);
        bf16x8 aq1 = ldb8(&qh_b[arow * 72 + 32 + lh * 8]);
        for (int nt = 0; nt < 16; nt++) {
            const int c = nt * 16 + lq;
            f32x4 acc = {0.f, 0.f, 0.f, 0.f};
            float wf[8];
#pragma unroll
            for (int j = 0; j < 8; j++)
                wf[j] = W_k[(size_t)(w * 64 + lh * 8 + j) * DM + c];
            acc = __builtin_amdgcn_mfma_f32_16x16x32_bf16(aq0, pack8(wf), acc, 0, 0, 0);
#pragma unroll
            for (int j = 0; j < 8; j++)
                wf[j] = W_k[(size_t)(w * 64 + 32 + lh * 8 + j) * DM + c];
            acc = __builtin_amdgcn_mfma_f32_16x16x32_bf16(aq1, pack8(wf), acc, 0, 0, 0);
            if (lane < 16) {
#pragma unroll
                for (int r = 0; r < 4; r++)
                    tmat_b[(r * 4 + w) * TMS + nt * 16 + lq] = f2bf(acc[r]);
            }
        }
    }
    __syncthreads();

    {
        bf16x8 btm[8];
#pragma unroll
        for (int cb = 0; cb < 8; cb++)
            btm[cb] = ldb8(&tmat_b[lq * TMS + cb * 32 + lh * 8]);
        const int nmt = (len + 15) >> 4;
        for (int t = w; t < nmt; t += 4) {
            const int e = t * 16 + lq;
            const int ec = (e < len) ? e : (len - 1);
            const float* krow = &k[(size_t)(start + ec) * DM + lh * 8];
            f32x4 acc = {0.f, 0.f, 0.f, 0.f};
#pragma unroll
            for (int cb = 0; cb < 8; cb++) {
                float4 k0 = *(const float4*)&krow[cb * 32];
                float4 k1 = *(const float4*)&krow[cb * 32 + 4];
                float kf[8] = {k0.x, k0.y, k0.z, k0.w, k1.x, k1.y, k1.z, k1.w};
                acc = __builtin_amdgcn_mfma_f32_16x16x32_bf16(pack8(kf), btm[cb], acc, 0, 0, 0);
            }
#pragma unroll
            for (int r = 0; r < 4; r++) plog[t * 16 + lh * 4 + r][lq] = acc[r] * scale;
        }
    }
    __syncthreads();

    const int nkc = (len + 31) >> 5;
    {
        float m = -3.0e38f;
        for (int e = rg; e < len; e += 16) m = fmaxf(m, plog[e][cc]);
        red[rg][cc] = m;
        __syncthreads();
        if (tid < 16) {
            float mm = red[0][tid];
            for (int i2 = 1; i2 < 16; i2++) mm = fmaxf(mm, red[i2][tid]);
            mx[tid] = mm;
        }
        __syncthreads();
        const float mm = mx[cc];
        float s = 0.f;
        for (int e = rg; e < len; e += 16) {
            float ex = __expf(plog[e][cc] - mm);
            plog[e][cc] = ex;
            s += ex;
        }
        red[rg][cc] = s;
        __syncthreads();
        if (tid < 16) {
            float ss = red[0][tid];
            for (int i2 = 1; i2 < 16; i2++) ss += red[i2][tid];
            mx[tid] = 1.0f / ss;
        }
        __syncthreads();
        const float inv = mx[cc];
        const int padlen = nkc * 32;
        for (int e = rg; e < padlen; e += 16) {
            float pv = (e < len) ? plog[e][cc] * inv : 0.f;
            pT[cc * 136 + e] = f2bf(pv);
        }
    }
    __syncthreads();

    {
        f32x4 uacc[4];
#pragma unroll
        for (int nt = 0; nt < 4; nt++) uacc[nt] = {0.f, 0.f, 0.f, 0.f};
        const int c0 = w * 64;
#pragma unroll
        for (int kc = 0; kc < 4; kc++) {
            if (kc < nkc) {
                bf16x8 ap = ldb8(&pT[lq * 136 + kc * 32 + lh * 8]);
#pragma unroll
                for (int nt = 0; nt < 4; nt++) {
                    float bf[8];
#pragma unroll
                    for (int j = 0; j < 8; j++) {
                        int e = kc * 32 + lh * 8 + j;
                        int ecl = (e < len) ? e : (len - 1);
                        bf[j] = v[(size_t)(start + ecl) * DM + c0 + nt * 16 + lq];
                    }
                    uacc[nt] = __builtin_amdgcn_mfma_f32_16x16x32_bf16(ap, pack8(bf), uacc[nt], 0, 0, 0);
                }
            }
        }
#pragma unroll
        for (int nt = 0; nt < 4; nt++) {
#pragma unroll
            for (int r = 0; r < 4; r++) {
                const int row = lh * 4 + r;
                const int a = row >> 2, b = row & 3;
                u_b[a * 1032 + b * 256 + c0 + nt * 16 + lq] = f2bf(uacc[nt][r]);
            }
        }
    }
    __syncthreads();

    {
        const int arow = (lq < 3) ? lq : 3;
        f32x4 hacc = {0.f, 0.f, 0.f, 0.f};
        for (int kc = 0; kc < 32; kc++) {
            bf16x8 au = ldb8(&u_b[arow * 1032 + kc * 32 + lh * 8]);
            const int kk = kc * 32 + lh * 8;
            const float* wr = &W_v[(size_t)((kk >> 8) * 64 + w * 16 + lq) * DM + (kk & 255)];
            float4 w0 = *(const float4*)&wr[0];
            float4 w1 = *(const float4*)&wr[4];
            float wf[8] = {w0.x, w0.y, w0.z, w0.w, w1.x, w1.y, w1.z, w1.w};
            hacc = __builtin_amdgcn_mfma_f32_16x16x32_bf16(au, pack8(wf), hacc, 0, 0, 0);
        }
        if (lane < 16) {
#pragma unroll
            for (int r = 0; r < 4; r++) hid[r * 64 + w * 16 + lq] = hacc[r];
        }
    }
    __syncthreads();

    for (int i = 0; i < 16; i++) {
        const int m = i * 16 + rg;
        float acc = 0.f;
#pragma unroll
        for (int j4 = 0; j4 < 4; j4++) {
            const int c0 = j4 * 64 + cc * 4;
            float4 w4 = *(const float4*)&W_out[m * DM + c0];
            float4 h4 = *(const float4*)&hid[c0];
            acc += w4.x * h4.x + w4.y * h4.y + w4.z * h4.z + w4.w * h4.w;
        }
#pragma unroll
        for (int off = 8; off; off >>= 1) acc += __shfl_down(acc, off, 16);
        if (cc == 0) nh[m] = b_out[m] + acc;
    }
    __syncthreads();

    const int rv = rev[0];
    const int src = (rv == 0) ? pair[0] : pair[1];
    const int tar = (rv == 0) ? pair[1] : pair[0];
    float val;
    if (tok == src || tok == tar) {
        qrow[tid] = path_result[tid];
        __syncthreads();
        const float* x1 = (tok == src) ? nh : qrow;
        const float* x2 = (tok == src) ? qrow : nh;
        float acc = 0.f;
        for (int n = 0; n < 256; n += 4) {
            float4 w4 = *(const float4*)&W_agg[(size_t)tid * 512 + n];
            acc += w4.x * x1[n] + w4.y * x1[n + 1] + w4.z * x1[n + 2] + w4.w * x1[n + 3];
        }
        for (int n = 0; n < 256; n += 4) {
            float4 w4 = *(const float4*)&W_agg[(size_t)tid * 512 + 256 + n];
            acc += w4.x * x2[n] + w4.y * x2[n + 1] + w4.z * x2[n + 2] + w4.w * x2[n + 3];
        }
        val = acc;
    } else {
        val = nh[tid];
    }
    out[(size_t)tok * DM + tid] = val;
}

// -------------------- launcher --------------------
extern "C" void kernel_launch(void* const* d_in, const int* in_sizes, int n_in,
                              void* d_out, int out_size, void* d_ws, size_t ws_size,
                              hipStream_t stream) {
    const float* path    = (const float*)d_in[0];
    const float* q       = (const float*)d_in[2];
    const float* k       = (const float*)d_in[3];
    const float* v       = (const float*)d_in[4];
    const int*   edge_len  = (const int*)d_in[6];
    const int*   token_ids = (const int*)d_in[7];
    const int*   pair      = (const int*)d_in[8];
    const int*   rev       = (const int*)d_in[9];
    const float* W_qpair = (const float*)d_in[10];
    const float* W_pk    = (const float*)d_in[11];
    const float* W_pv    = (const float*)d_in[12];
    const float* W_q     = (const float*)d_in[13];
    const float* W_k     = (const float*)d_in[14];
    const float* W_v     = (const float*)d_in[15];
    const float* W_out   = (const float*)d_in[16];
    const float* b_out   = (const float*)d_in[17];
    const float* W_agg   = (const float*)d_in[18];
    float* out = (float*)d_out;

    char* base = (char*)d_ws;
    int*    starts      = (int*)(base + 0);              // 16 KB
    float*  path_result = (float*)(base + 16384);        // 1 KB
    float*  pv_ws       = (float*)(base + 17408);        // 64 KB
    float*  logits_ws   = (float*)(base + 82944);        // 1 KB
    ushortT* WQb        = (ushortT*)(base + 83968);      // 128 KB
    ushortT* WKTb       = (ushortT*)(base + 215040);     // 128 KB
    ushortT* WVb        = (ushortT*)(base + 346112);     // 128 KB
    ushortT* WOb        = (ushortT*)(base + 477184);     // 128 KB
    ushortT* tmat_u     = (ushortT*)(base + 608256);     // 32 MB
    const size_t NEED = 608256 + 33554432;

    if (ws_size >= NEED) {
        prep_kernel<<<dim3(3137), dim3(256), 0, stream>>>(
            q, out, edge_len, starts, path, pair, rev, W_qpair, W_pk, W_pv,
            pv_ws, logits_ws, W_q, W_k, W_v, W_out, WQb, WKTb, WVb, WOb);
        qhtmatC_kernel<<<dim3(257), dim3(256), 0, stream>>>(
            q, token_ids, WQb, WKTb, tmat_u, pv_ws, logits_ws, W_out, b_out,
            out + (size_t)SEN * DM, path_result);
        edge_kernel<<<dim3(NG), dim3(256), 0, stream>>>(k, v, edge_len, starts, tmat_u);
        hidnhagg_kernel<<<dim3(256), dim3(256), 0, stream>>>(
            tmat_u, WVb, WOb, b_out, token_ids, pair, rev, W_agg, path_result, out);
    } else {
        copy_kernel<<<dim3(2048), dim3(256), 0, stream>>>(q, out);
        scan_kernel<<<dim3(1), dim3(256), 0, stream>>>(edge_len, starts);
        pathB_kernel<<<dim3(PLEN), dim3(256), 0, stream>>>(path, q, pair, rev, W_qpair,
                                                           W_pk, W_pv, pv_ws, logits_ws);
        pathC_kernel<<<dim3(1), dim3(256), 0, stream>>>(pv_ws, logits_ws, W_out, b_out,
                                                        out + (size_t)SEN * DM, path_result);
        group_kernel<<<dim3(NG), dim3(256), 0, stream>>>(q, k, v, edge_len, token_ids, pair,
                                                         rev, W_q, W_k, W_v, W_out, b_out,
                                                         W_agg, starts, path_result, out);
    }
}

// Round 13
// 273.115 us; speedup vs baseline: 1.1705x; 1.1034x over previous
//
#include <hip/hip_runtime.h>
#include <hip/hip_bf16.h>

#define H 4
#define DK 64
#define DM 256
#define SEN 8192
#define NG 4096
#define ETOT 262144
#define PLEN 64
#define MAXE 128

typedef unsigned short ushortT;
typedef __attribute__((ext_vector_type(8))) __bf16 bf16x8;
typedef __attribute__((ext_vector_type(8))) unsigned short us8;
typedef __attribute__((ext_vector_type(4))) unsigned short us4;
typedef __attribute__((ext_vector_type(4))) float f32x4;

#define TMS 264   // fallback tmat_b row stride
#define KVSF 260  // edge k/v f32 stage row stride (floats; 1040B, 16B-aligned)

// ---- old bit-exact helpers (fallback kernel) ----
__device__ __forceinline__ ushortT f2bf(float f) {
    unsigned u = __float_as_uint(f);
    u += 0x7FFF + ((u >> 16) & 1);
    return (ushortT)(u >> 16);
}
__device__ __forceinline__ bf16x8 ldb8(const ushortT* p) {
    us8 v = *(const us8*)p;
    return __builtin_bit_cast(bf16x8, v);
}
__device__ __forceinline__ bf16x8 pack8(const float* f) {
    us8 v;
#pragma unroll
    for (int j = 0; j < 8; j++) v[j] = f2bf(f[j]);
    return __builtin_bit_cast(bf16x8, v);
}
// ---- fast native-cast helpers ----
__device__ __forceinline__ ushortT sbf(float f) {
    return __builtin_bit_cast(ushortT, (__bf16)f);
}
__device__ __forceinline__ bf16x8 pack8f(float4 a, float4 b) {
    bf16x8 r;
    r[0] = (__bf16)a.x; r[1] = (__bf16)a.y; r[2] = (__bf16)a.z; r[3] = (__bf16)a.w;
    r[4] = (__bf16)b.x; r[5] = (__bf16)b.y; r[6] = (__bf16)b.z; r[7] = (__bf16)b.w;
    return r;
}
// ---- async global->LDS: one wave stages one contiguous 1KB row ----
__device__ __forceinline__ void gload_row16(const float* g, float* lds) {
    __builtin_amdgcn_global_load_lds(
        (const __attribute__((address_space(1))) void*)g,
        (__attribute__((address_space(3))) void*)lds, 16, 0, 0);
}

// ==================== FAST PATH: 4 launches ====================

// -------------------- L1: prep = copy ∥ wprep ∥ scan ∥ pathB --------------------
__global__ __launch_bounds__(256) void prep_kernel(
    const float* __restrict__ q, float* __restrict__ out,
    const int* __restrict__ edge_len, int* __restrict__ starts,
    const float* __restrict__ path, const int* __restrict__ pair,
    const int* __restrict__ rev, const float* __restrict__ W_qpair,
    const float* __restrict__ W_pk, const float* __restrict__ W_pv,
    float* __restrict__ pv_ws, float* __restrict__ logits_ws,
    const float* __restrict__ W_q, const float* __restrict__ W_k,
    const float* __restrict__ W_v, const float* __restrict__ W_out,
    ushortT* __restrict__ WQb, ushortT* __restrict__ WKTb,
    ushortT* __restrict__ WVb, ushortT* __restrict__ WOb) {
    __shared__ int part[256];
    __shared__ float cat[512];
    __shared__ float pq[256];
    __shared__ float prow[256];
    __shared__ float lp[256];
    const int b = blockIdx.x;
    const int tid = threadIdx.x;
    if (b < 2048) {                       // ---- copy q -> out ----
        const size_t i = (size_t)b * 256 + tid;
        ((float4*)out)[i] = ((const float4*)q)[i];
    } else if (b < 3072) {                // ---- weight prep ----
        const int idx = (b - 2048) * 256 + tid;
        const int sel = idx >> 16;
        const int i = idx & 65535;
        if (sel == 0) {
            WQb[i] = sbf(W_q[i]);
        } else if (sel == 1) {
            const int c = i >> 8, d = i & 255;
            WKTb[i] = sbf(W_k[d * DM + c]);
        } else if (sel == 2) {
            WVb[i] = sbf(W_v[i]);
        } else {
            WOb[i] = sbf(W_out[i]);
        }
    } else if (b == 3072) {               // ---- prefix scan ----
        const int base = tid * 16;
        int loc[16];
        int s = 0;
#pragma unroll
        for (int i = 0; i < 16; i++) { loc[i] = s; s += edge_len[base + i]; }
        part[tid] = s;
        __syncthreads();
        if (tid == 0) {
            int acc = 0;
            for (int i = 0; i < 256; i++) { int t = part[i]; part[i] = acc; acc += t; }
        }
        __syncthreads();
        const int off = part[tid];
#pragma unroll
        for (int i = 0; i < 16; i++) starts[base + i] = off + loc[i];
    } else {                              // ---- pathB, p = b - 3073 ----
        const int p = b - 3073;
        const int rv = rev[0];
        const int src = (rv == 0) ? pair[0] : pair[1];
        const int tar = (rv == 0) ? pair[1] : pair[0];
        cat[tid] = q[(size_t)src * DM + tid];
        cat[256 + tid] = q[(size_t)tar * DM + tid];
        prow[tid] = path[p * DM + tid];
        __syncthreads();
        float acc = 0.f;
        for (int c = 0; c < 512; c += 4) {
            float4 w4 = *(const float4*)&W_qpair[(size_t)tid * 512 + c];
            acc += w4.x * cat[c] + w4.y * cat[c + 1] + w4.z * cat[c + 2] + w4.w * cat[c + 3];
        }
        pq[tid] = acc;
        __syncthreads();
        float pkv = 0.f, pvv = 0.f;
        for (int c = 0; c < 256; c += 4) {
            float4 a4 = *(const float4*)&W_pk[tid * DM + c];
            float4 b4 = *(const float4*)&W_pv[tid * DM + c];
            float4 x4 = *(const float4*)&prow[c];
            pkv += a4.x * x4.x + a4.y * x4.y + a4.z * x4.z + a4.w * x4.w;
            pvv += b4.x * x4.x + b4.y * x4.y + b4.z * x4.z + b4.w * x4.w;
        }
        pv_ws[p * DM + tid] = pvv;
        lp[tid] = pq[tid] * pkv;
        __syncthreads();
        if (tid < H) {
            float s = 0.f;
            for (int d = 0; d < DK; d++) s += lp[tid * DK + d];
            logits_ws[tid * PLEN + p] = s * 0.125f;
        }
    }
}

// -------------------- L2: qhtmat (b<256) ∥ pathC (b==256) --------------------
__global__ __launch_bounds__(256) void qhtmatC_kernel(
    const float* __restrict__ q, const int* __restrict__ token_ids,
    const ushortT* __restrict__ WQb, const ushortT* __restrict__ WKTb,
    ushortT* __restrict__ tmat_u,
    const float* __restrict__ pv_ws, const float* __restrict__ logits_ws,
    const float* __restrict__ W_out, const float* __restrict__ b_out,
    float* __restrict__ att_out, float* __restrict__ path_result) {
    __shared__ ushortT Al[16 * 264];
    __shared__ ushortT QHs[16 * 264];
    __shared__ float att[256];
    __shared__ float pvals[256];
    const int tid = threadIdx.x;
    if (blockIdx.x == 256) {              // ---- pathC ----
        att[tid] = logits_ws[tid];
        __syncthreads();
        if (tid < H) {
            float m = -3.0e38f;
            for (int p = 0; p < PLEN; p++) m = fmaxf(m, att[tid * PLEN + p]);
            float s = 0.f;
            for (int p = 0; p < PLEN; p++) {
                float e = __expf(att[tid * PLEN + p] - m);
                att[tid * PLEN + p] = e;
                s += e;
            }
            float inv = 1.f / s;
            for (int p = 0; p < PLEN; p++) att[tid * PLEN + p] *= inv;
        }
        __syncthreads();
        att_out[tid] = att[tid];
        {
            const int h = tid >> 6;
            float a = 0.f;
            for (int p = 0; p < PLEN; p++) a += att[h * PLEN + p] * pv_ws[p * DM + tid];
            pvals[tid] = a;
        }
        __syncthreads();
        {
            float a = b_out[tid];
            for (int c = 0; c < 256; c += 4) {
                float4 w4 = *(const float4*)&W_out[tid * DM + c];
                a += w4.x * pvals[c] + w4.y * pvals[c + 1] + w4.z * pvals[c + 2] + w4.w * pvals[c + 3];
            }
            path_result[tid] = a;
        }
        return;
    }
    // ---- qhtmat, 16 groups/block ----
    const int g0 = blockIdx.x * 16;
    const int lane = tid & 63, w = tid >> 6, lq = lane & 15, lh = lane >> 4;
    {
        const int m = tid >> 4;
        const int c0 = (tid & 15) * 16;
        const int tok = token_ids[g0 + m];
        const float* qr = &q[(size_t)tok * DM + c0];
#pragma unroll
        for (int i = 0; i < 4; i++) {
            float4 v4 = *(const float4*)&qr[i * 4];
            us4 o;
            o[0] = sbf(v4.x); o[1] = sbf(v4.y); o[2] = sbf(v4.z); o[3] = sbf(v4.w);
            *(us4*)&Al[m * 264 + c0 + i * 4] = o;
        }
    }
    __syncthreads();
    {
        bf16x8 af[8];
#pragma unroll
        for (int kk = 0; kk < 8; kk++) af[kk] = ldb8(&Al[lq * 264 + kk * 32 + lh * 8]);
#pragma unroll
        for (int ntl = 0; ntl < 4; ntl++) {
            const int nt = w * 4 + ntl;
            f32x4 acc = {0.f, 0.f, 0.f, 0.f};
#pragma unroll
            for (int kk = 0; kk < 8; kk++) {
                bf16x8 bf = ldb8(&WQb[(nt * 16 + lq) * 256 + kk * 32 + lh * 8]);
                acc = __builtin_amdgcn_mfma_f32_16x16x32_bf16(af[kk], bf, acc, 0, 0, 0);
            }
#pragma unroll
            for (int r = 0; r < 4; r++)
                QHs[(lh * 4 + r) * 264 + nt * 16 + lq] = sbf(acc[r]);
        }
    }
    __syncthreads();
    for (int ab = 0; ab < 16; ab++) {
        const int a = ab >> 2, bb = ab & 3;
        bf16x8 a0 = ldb8(&QHs[lq * 264 + a * 64 + lh * 8]);
        bf16x8 a1 = ldb8(&QHs[lq * 264 + a * 64 + 32 + lh * 8]);
#pragma unroll
        for (int ntl = 0; ntl < 4; ntl++) {
            const int nt = w * 4 + ntl;
            f32x4 acc = {0.f, 0.f, 0.f, 0.f};
            bf16x8 b0 = ldb8(&WKTb[(nt * 16 + lq) * 256 + bb * 64 + lh * 8]);
            acc = __builtin_amdgcn_mfma_f32_16x16x32_bf16(a0, b0, acc, 0, 0, 0);
            bf16x8 b1 = ldb8(&WKTb[(nt * 16 + lq) * 256 + bb * 64 + 32 + lh * 8]);
            acc = __builtin_amdgcn_mfma_f32_16x16x32_bf16(a1, b1, acc, 0, 0, 0);
#pragma unroll
            for (int r = 0; r < 4; r++)
                tmat_u[((size_t)(g0 + lh * 4 + r) * 16 + ab) * 256 + nt * 16 + lq] =
                    sbf(acc[r]);
        }
    }
}

// -------------------- L3: edge attention, async global_load_lds staging --------
__global__ __launch_bounds__(256, 3) void edge_kernel(
    const float* __restrict__ k, const float* __restrict__ v,
    const int* __restrict__ edge_len, const int* __restrict__ starts,
    ushortT* __restrict__ tmat_u) {
    const int g = blockIdx.x;
    const int tid = threadIdx.x;
    const float scale = 0.125f;
    __shared__ float plog[128][17];
    __shared__ ushortT pT[16 * 136];
    __shared__ float red[16][16];
    __shared__ float mx[16];
    __shared__ float kvf[32 * KVSF];      // f32 stage, 32 rows x 256 (+4 pad)
    const int start = starts[g];
    const int len = edge_len[g];
    const int lane = tid & 63, w = tid >> 6, lq = lane & 15, lh = lane >> 4;
    const int rg = tid >> 4, cc = tid & 15;
    const int nkc = (len + 31) >> 5;      // 1..4  (32-row chunks)
    const int nmt = (len + 15) >> 4;      // 1..8  (16-row logit tiles)

    // hoist tmat fragments
    bf16x8 btm[8];
#pragma unroll
    for (int cb = 0; cb < 8; cb++)
        btm[cb] = ldb8(&tmat_u[((size_t)g * 16 + lq) * 256 + cb * 32 + lh * 8]);

    // ---------- pass 1: k staged via async DMA, 32-row chunks ----------
    for (int c = 0; c < nkc; c++) {
        // each wave issues 8 independent 1KB row-DMAs (no VGPR round-trip)
#pragma unroll
        for (int i = 0; i < 8; i++) {
            const int row = i * 4 + w;                 // wave-uniform 0..31
            const int gr = c * 32 + row;
            const int grc = (gr < len) ? gr : (len - 1);
            gload_row16(&k[(size_t)(start + grc) * DM + lane * 4], &kvf[row * KVSF]);
        }
        __syncthreads();                               // single vmcnt drain
        const int t = c * 2 + w;                       // waves 0,1 compute tiles
        if (w < 2 && t < nmt) {
            f32x4 acc = {0.f, 0.f, 0.f, 0.f};
#pragma unroll
            for (int cb = 0; cb < 8; cb++) {
                float4 f0 = *(const float4*)&kvf[(w * 16 + lq) * KVSF + cb * 32 + lh * 8];
                float4 f1 = *(const float4*)&kvf[(w * 16 + lq) * KVSF + cb * 32 + lh * 8 + 4];
                acc = __builtin_amdgcn_mfma_f32_16x16x32_bf16(pack8f(f0, f1), btm[cb], acc, 0, 0, 0);
            }
#pragma unroll
            for (int r = 0; r < 4; r++) plog[t * 16 + lh * 4 + r][lq] = acc[r] * scale;
        }
        __syncthreads();
    }

    // ---------- softmax over edges (per ab = cc) ----------
    {
        float m = -3.0e38f;
        for (int e = rg; e < len; e += 16) m = fmaxf(m, plog[e][cc]);
        red[rg][cc] = m;
        __syncthreads();
        if (tid < 16) {
            float mm = red[0][tid];
            for (int i2 = 1; i2 < 16; i2++) mm = fmaxf(mm, red[i2][tid]);
            mx[tid] = mm;
        }
        __syncthreads();
        const float mm = mx[cc];
        float s = 0.f;
        for (int e = rg; e < len; e += 16) {
            float ex = __expf(plog[e][cc] - mm);
            plog[e][cc] = ex;
            s += ex;
        }
        red[rg][cc] = s;
        __syncthreads();
        if (tid < 16) {
            float ss = red[0][tid];
            for (int i2 = 1; i2 < 16; i2++) ss += red[i2][tid];
            mx[tid] = 1.0f / ss;
        }
        __syncthreads();
        const float inv = mx[cc];
        const int padlen = nkc * 32;
        for (int e = rg; e < padlen; e += 16) {
            float pv = (e < len) ? plog[e][cc] * inv : 0.f;
            pT[cc * 136 + e] = sbf(pv);
        }
    }
    __syncthreads();

    // ---------- pass 2: v staged via async DMA, 32-row chunks ----------
    {
        f32x4 uacc[4];
#pragma unroll
        for (int nt = 0; nt < 4; nt++) uacc[nt] = {0.f, 0.f, 0.f, 0.f};
        for (int kc = 0; kc < nkc; kc++) {
#pragma unroll
            for (int i = 0; i < 8; i++) {
                const int row = i * 4 + w;
                const int gr = kc * 32 + row;
                const int grc = (gr < len) ? gr : (len - 1);   // clamp: real data
                gload_row16(&v[(size_t)(start + grc) * DM + lane * 4], &kvf[row * KVSF]);
            }
            __syncthreads();
            bf16x8 ap = ldb8(&pT[lq * 136 + kc * 32 + lh * 8]);
#pragma unroll
            for (int nt = 0; nt < 4; nt++) {
                bf16x8 bv;
#pragma unroll
                for (int j = 0; j < 8; j++)
                    bv[j] = (__bf16)kvf[(lh * 8 + j) * KVSF + w * 64 + nt * 16 + lq];
                uacc[nt] = __builtin_amdgcn_mfma_f32_16x16x32_bf16(ap, bv, uacc[nt], 0, 0, 0);
            }
            __syncthreads();
        }
        const int c0 = w * 64;
#pragma unroll
        for (int nt = 0; nt < 4; nt++) {
#pragma unroll
            for (int r = 0; r < 4; r++) {
                const int ab = lh * 4 + r;
                tmat_u[((size_t)g * 16 + ab) * 256 + c0 + nt * 16 + lq] = sbf(uacc[nt][r]);
            }
        }
    }
}

// -------------------- L4: HID + NH + inline agg fixup --------------------
__global__ __launch_bounds__(256) void hidnhagg_kernel(
    const ushortT* __restrict__ Ub, const ushortT* __restrict__ WVb,
    const ushortT* __restrict__ WOb, const float* __restrict__ b_out,
    const int* __restrict__ token_ids, const int* __restrict__ pair,
    const int* __restrict__ rev, const float* __restrict__ W_agg,
    const float* __restrict__ path_result, float* __restrict__ out) {
    __shared__ ushortT HIDs[16 * 264];
    __shared__ float nhs[2][260];
    __shared__ float prb[256];
    __shared__ int flagrow[2];
    const int tid = threadIdx.x;
    const int g0 = blockIdx.x * 16;
    const int lane = tid & 63, w = tid >> 6, lq = lane & 15, lh = lane >> 4;
    if (tid < 2) flagrow[tid] = -1;
    prb[tid] = path_result[tid];
#pragma unroll
    for (int a = 0; a < 4; a++) {
        f32x4 acc = {0.f, 0.f, 0.f, 0.f};
        for (int kk = 0; kk < 32; kk++) {
            const int kbase = kk * 32 + lh * 8;
            bf16x8 af = ldb8(&Ub[((size_t)(g0 + lq) * 16 + a * 4) * 256 + kbase]);
            bf16x8 bf = ldb8(&WVb[(size_t)((kbase >> 8) * 64 + w * 16 + lq) * 256 + (kbase & 255)]);
            acc = __builtin_amdgcn_mfma_f32_16x16x32_bf16(af, bf, acc, 0, 0, 0);
        }
#pragma unroll
        for (int r = 0; r < 4; r++)
            HIDs[(lh * 4 + r) * 264 + a * 64 + w * 16 + lq] = sbf(acc[r]);
    }
    __syncthreads();
    bf16x8 af2[8];
#pragma unroll
    for (int kk = 0; kk < 8; kk++) af2[kk] = ldb8(&HIDs[lq * 264 + kk * 32 + lh * 8]);
    const int rv = rev[0];
    const int src = (rv == 0) ? pair[0] : pair[1];
    const int tar = (rv == 0) ? pair[1] : pair[0];
    int toks[4];
#pragma unroll
    for (int r = 0; r < 4; r++) {
        toks[r] = token_ids[g0 + lh * 4 + r];
        if (toks[r] == src) flagrow[0] = lh * 4 + r;
        else if (toks[r] == tar) flagrow[1] = lh * 4 + r;
    }
#pragma unroll
    for (int ntl = 0; ntl < 4; ntl++) {
        const int nt = w * 4 + ntl;
        f32x4 acc = {0.f, 0.f, 0.f, 0.f};
#pragma unroll
        for (int kk = 0; kk < 8; kk++) {
            bf16x8 bf = ldb8(&WOb[(nt * 16 + lq) * 256 + kk * 32 + lh * 8]);
            acc = __builtin_amdgcn_mfma_f32_16x16x32_bf16(af2[kk], bf, acc, 0, 0, 0);
        }
        const int n = nt * 16 + lq;
        const float bo = b_out[n];
#pragma unroll
        for (int r = 0; r < 4; r++) {
            const float val = acc[r] + bo;
            if (toks[r] == src) nhs[0][n] = val;
            else if (toks[r] == tar) nhs[1][n] = val;
            else out[(size_t)toks[r] * DM + n] = val;
        }
    }
    __syncthreads();
#pragma unroll
    for (int s = 0; s < 2; s++) {
        if (flagrow[s] >= 0) {
            const float* x1 = (s == 0) ? nhs[0] : prb;
            const float* x2 = (s == 0) ? prb : nhs[1];
            float acc = 0.f;
            for (int n = 0; n < 256; n += 4) {
                float4 w4 = *(const float4*)&W_agg[(size_t)tid * 512 + n];
                acc += w4.x * x1[n] + w4.y * x1[n + 1] + w4.z * x1[n + 2] + w4.w * x1[n + 3];
            }
            for (int n = 0; n < 256; n += 4) {
                float4 w4 = *(const float4*)&W_agg[(size_t)tid * 512 + 256 + n];
                acc += w4.x * x2[n] + w4.y * x2[n + 1] + w4.z * x2[n + 2] + w4.w * x2[n + 3];
            }
            out[(size_t)((s == 0) ? src : tar) * DM + tid] = acc;
        }
    }
}

// ==================== FALLBACK PATH (ws too small) ====================

__global__ __launch_bounds__(256) void scan_kernel(const int* __restrict__ edge_len,
                                                   int* __restrict__ starts) {
    __shared__ int part[256];
    const int tid = threadIdx.x;
    const int base = tid * 16;
    int loc[16];
    int s = 0;
#pragma unroll
    for (int i = 0; i < 16; i++) { loc[i] = s; s += edge_len[base + i]; }
    part[tid] = s;
    __syncthreads();
    if (tid == 0) {
        int acc = 0;
        for (int i = 0; i < 256; i++) { int t = part[i]; part[i] = acc; acc += t; }
    }
    __syncthreads();
    const int off = part[tid];
#pragma unroll
    for (int i = 0; i < 16; i++) starts[base + i] = off + loc[i];
}

__global__ void copy_kernel(const float* __restrict__ q, float* __restrict__ out) {
    const size_t i = (size_t)blockIdx.x * blockDim.x + threadIdx.x;
    ((float4*)out)[i] = ((const float4*)q)[i];
}

__global__ __launch_bounds__(256) void pathB_kernel(
    const float* __restrict__ path, const float* __restrict__ q,
    const int* __restrict__ pair, const int* __restrict__ rev,
    const float* __restrict__ W_qpair, const float* __restrict__ W_pk,
    const float* __restrict__ W_pv,
    float* __restrict__ pv_ws, float* __restrict__ logits_ws) {
    __shared__ float cat[512];
    __shared__ float pq[256];
    __shared__ float prow[256];
    __shared__ float lp[256];
    const int p = blockIdx.x;
    const int tid = threadIdx.x;
    const int rv = rev[0];
    const int src = (rv == 0) ? pair[0] : pair[1];
    const int tar = (rv == 0) ? pair[1] : pair[0];
    cat[tid] = q[(size_t)src * DM + tid];
    cat[256 + tid] = q[(size_t)tar * DM + tid];
    prow[tid] = path[p * DM + tid];
    __syncthreads();
    float acc = 0.f;
    for (int c = 0; c < 512; c += 4) {
        float4 w4 = *(const float4*)&W_qpair[(size_t)tid * 512 + c];
        acc += w4.x * cat[c] + w4.y * cat[c + 1] + w4.z * cat[c + 2] + w4.w * cat[c + 3];
    }
    pq[tid] = acc;
    __syncthreads();
    float pkv = 0.f, pvv = 0.f;
    for (int c = 0; c < 256; c += 4) {
        float4 a4 = *(const float4*)&W_pk[tid * DM + c];
        float4 b4 = *(const float4*)&W_pv[tid * DM + c];
        float4 x4 = *(const float4*)&prow[c];
        pkv += a4.x * x4.x + a4.y * x4.y + a4.z * x4.z + a4.w * x4.w;
        pvv += b4.x * x4.x + b4.y * x4.y + b4.z * x4.z + b4.w * x4.w;
    }
    pv_ws[p * DM + tid] = pvv;
    lp[tid] = pq[tid] * pkv;
    __syncthreads();
    if (tid < H) {
        float s = 0.f;
        for (int d = 0; d < DK; d++) s += lp[tid * DK + d];
        logits_ws[tid * PLEN + p] = s * 0.125f;
    }
}

__global__ __launch_bounds__(256) void pathC_kernel(
    const float* __restrict__ pv_ws, const float* __restrict__ logits_ws,
    const float* __restrict__ W_out, const float* __restrict__ b_out,
    float* __restrict__ att_out, float* __restrict__ path_result) {
    __shared__ float att[256];
    __shared__ float pvals[256];
    const int tid = threadIdx.x;
    att[tid] = logits_ws[tid];
    __syncthreads();
    if (tid < H) {
        float m = -3.0e38f;
        for (int p = 0; p < PLEN; p++) m = fmaxf(m, att[tid * PLEN + p]);
        float s = 0.f;
        for (int p = 0; p < PLEN; p++) {
            float e = __expf(att[tid * PLEN + p] - m);
            att[tid * PLEN + p] = e;
            s += e;
        }
        float inv = 1.f / s;
        for (int p = 0; p < PLEN; p++) att[tid * PLEN + p] *= inv;
    }
    __syncthreads();
    att_out[tid] = att[tid];
    {
        const int h = tid >> 6;
        float a = 0.f;
        for (int p = 0; p < PLEN; p++) a += att[h * PLEN + p] * pv_ws[p * DM + tid];
        pvals[tid] = a;
    }
    __syncthreads();
    {
        float a = b_out[tid];
        for (int c = 0; c < 256; c += 4) {
            float4 w4 = *(const float4*)&W_out[tid * DM + c];
            a += w4.x * pvals[c] + w4.y * pvals[c + 1] + w4.z * pvals[c + 2] + w4.w * pvals[c + 3];
        }
        path_result[tid] = a;
    }
}

__global__ __launch_bounds__(256, 4) void group_kernel(
    const float* __restrict__ q, const float* __restrict__ k, const float* __restrict__ v,
    const int* __restrict__ edge_len, const int* __restrict__ token_ids,
    const int* __restrict__ pair, const int* __restrict__ rev,
    const float* __restrict__ W_q,
    const float* __restrict__ W_k, const float* __restrict__ W_v,
    const float* __restrict__ W_out, const float* __restrict__ b_out,
    const float* __restrict__ W_agg,
    const int* __restrict__ starts, const float* __restrict__ path_result,
    float* __restrict__ out) {
    const int g = blockIdx.x;
    const int tid = threadIdx.x;
    const float scale = 0.125f;

    __shared__ float qrow[256];
    __shared__ float qh[256];
    __shared__ ushortT qh_b[4 * 72];
    __shared__ ushortT tmat_b[16 * TMS];
    __shared__ float plog[128][17];
    __shared__ ushortT pT[16 * 136];
    __shared__ ushortT u_b[4 * 1032];
    __shared__ float hid[256];
    __shared__ float nh[256];
    __shared__ float red[16][16];
    __shared__ float mx[16];

    const int tok = token_ids[g];
    const int start = starts[g];
    const int len = edge_len[g];

    const int lane = tid & 63;
    const int w = tid >> 6;
    const int lq = lane & 15;
    const int lh = lane >> 4;
    const int rg = tid >> 4;
    const int cc = tid & 15;

    qrow[tid] = q[(size_t)tok * DM + tid];
    __syncthreads();

    for (int i = 0; i < 16; i++) {
        const int r = i * 16 + rg;
        float acc = 0.f;
#pragma unroll
        for (int j4 = 0; j4 < 4; j4++) {
            const int c0 = j4 * 64 + cc * 4;
            float4 w4 = *(const float4*)&W_q[r * DM + c0];
            float4 x4 = *(const float4*)&qrow[c0];
            acc += w4.x * x4.x + w4.y * x4.y + w4.z * x4.z + w4.w * x4.w;
        }
#pragma unroll
        for (int off = 8; off; off >>= 1) acc += __shfl_down(acc, off, 16);
        if (cc == 0) qh[r] = acc;
    }
    __syncthreads();
    qh_b[(tid >> 6) * 72 + (tid & 63)] = f2bf(qh[tid]);
    __syncthreads();

    {
        const int arow = (lq < 3) ? lq : 3;
        bf16x8 aq0 = ldb8(&qh_b[arow * 72 + lh * 8]);
        bf16x8 aq1 = ldb8(&qh_b[arow * 72 + 32 + lh * 8]);
        for (int nt = 0; nt < 16; nt++) {
            const int c = nt * 16 + lq;
            f32x4 acc = {0.f, 0.f, 0.f, 0.f};
            float wf[8];
#pragma unroll
            for (int j = 0; j < 8; j++)
                wf[j] = W_k[(size_t)(w * 64 + lh * 8 + j) * DM + c];
            acc = __builtin_amdgcn_mfma_f32_16x16x32_bf16(aq0, pack8(wf), acc, 0, 0, 0);
#pragma unroll
            for (int j = 0; j < 8; j++)
                wf[j] = W_k[(size_t)(w * 64 + 32 + lh * 8 + j) * DM + c];
            acc = __builtin_amdgcn_mfma_f32_16x16x32_bf16(aq1, pack8(wf), acc, 0, 0, 0);
            if (lane < 16) {
#pragma unroll
                for (int r = 0; r < 4; r++)
                    tmat_b[(r * 4 + w) * TMS + nt * 16 + lq] = f2bf(acc[r]);
            }
        }
    }
    __syncthreads();

    {
        bf16x8 btm[8];
#pragma unroll
        for (int cb = 0; cb < 8; cb++)
            btm[cb] = ldb8(&tmat_b[lq * TMS + cb * 32 + lh * 8]);
        const int nmt = (len + 15) >> 4;
        for (int t = w; t < nmt; t += 4) {
            const int e = t * 16 + lq;
            const int ec = (e < len) ? e : (len - 1);
            const float* krow = &k[(size_t)(start + ec) * DM + lh * 8];
            f32x4 acc = {0.f, 0.f, 0.f, 0.f};
#pragma unroll
            for (int cb = 0; cb < 8; cb++) {
                float4 k0 = *(const float4*)&krow[cb * 32];
                float4 k1 = *(const float4*)&krow[cb * 32 + 4];
                float kf[8] = {k0.x, k0.y, k0.z, k0.w, k1.x, k1.y, k1.z, k1.w};
                acc = __builtin_amdgcn_mfma_f32_16x16x32_bf16(pack8(kf), btm[cb], acc, 0, 0, 0);
            }
#pragma unroll
            for (int r = 0; r < 4; r++) plog[t * 16 + lh * 4 + r][lq] = acc[r] * scale;
        }
    }
    __syncthreads();

    const int nkc = (len + 31) >> 5;
    {
        float m = -3.0e38f;
        for (int e = rg; e < len; e += 16) m = fmaxf(m, plog[e][cc]);
        red[rg][cc] = m;
        __syncthreads();
        if (tid < 16) {
            float mm = red[0][tid];
            for (int i2 = 1; i2 < 16; i2++) mm = fmaxf(mm, red[i2][tid]);
            mx[tid] = mm;
        }
        __syncthreads();
        const float mm = mx[cc];
        float s = 0.f;
        for (int e = rg; e < len; e += 16) {
            float ex = __expf(plog[e][cc] - mm);
            plog[e][cc] = ex;
            s += ex;
        }
        red[rg][cc] = s;
        __syncthreads();
        if (tid < 16) {
            float ss = red[0][tid];
            for (int i2 = 1; i2 < 16; i2++) ss += red[i2][tid];
            mx[tid] = 1.0f / ss;
        }
        __syncthreads();
        const float inv = mx[cc];
        const int padlen = nkc * 32;
        for (int e = rg; e < padlen; e += 16) {
            float pv = (e < len) ? plog[e][cc] * inv : 0.f;
            pT[cc * 136 + e] = f2bf(pv);
        }
    }
    __syncthreads();

    {
        f32x4 uacc[4];
#pragma unroll
        for (int nt = 0; nt < 4; nt++) uacc[nt] = {0.f, 0.f, 0.f, 0.f};
        const int c0 = w * 64;
#pragma unroll
        for (int kc = 0; kc < 4; kc++) {
            if (kc < nkc) {
                bf16x8 ap = ldb8(&pT[lq * 136 + kc * 32 + lh * 8]);
#pragma unroll
                for (int nt = 0; nt < 4; nt++) {
                    float bf[8];
#pragma unroll
                    for (int j = 0; j < 8; j++) {
                        int e = kc * 32 + lh * 8 + j;
                        int ecl = (e < len) ? e : (len - 1);
                        bf[j] = v[(size_t)(start + ecl) * DM + c0 + nt * 16 + lq];
                    }
                    uacc[nt] = __builtin_amdgcn_mfma_f32_16x16x32_bf16(ap, pack8(bf), uacc[nt], 0, 0, 0);
                }
            }
        }
#pragma unroll
        for (int nt = 0; nt < 4; nt++) {
#pragma unroll
            for (int r = 0; r < 4; r++) {
                const int row = lh * 4 + r;
                const int a = row >> 2, b = row & 3;
                u_b[a * 1032 + b * 256 + c0 + nt * 16 + lq] = f2bf(uacc[nt][r]);
            }
        }
    }
    __syncthreads();

    {
        const int arow = (lq < 3) ? lq : 3;
        f32x4 hacc = {0.f, 0.f, 0.f, 0.f};
        for (int kc = 0; kc < 32; kc++) {
            bf16x8 au = ldb8(&u_b[arow * 1032 + kc * 32 + lh * 8]);
            const int kk = kc * 32 + lh * 8;
            const float* wr = &W_v[(size_t)((kk >> 8) * 64 + w * 16 + lq) * DM + (kk & 255)];
            float4 w0 = *(const float4*)&wr[0];
            float4 w1 = *(const float4*)&wr[4];
            float wf[8] = {w0.x, w0.y, w0.z, w0.w, w1.x, w1.y, w1.z, w1.w};
            hacc = __builtin_amdgcn_mfma_f32_16x16x32_bf16(au, pack8(wf), hacc, 0, 0, 0);
        }
        if (lane < 16) {
#pragma unroll
            for (int r = 0; r < 4; r++) hid[r * 64 + w * 16 + lq] = hacc[r];
        }
    }
    __syncthreads();

    for (int i = 0; i < 16; i++) {
        const int m = i * 16 + rg;
        float acc = 0.f;
#pragma unroll
        for (int j4 = 0; j4 < 4; j4++) {
            const int c0 = j4 * 64 + cc * 4;
            float4 w4 = *(const float4*)&W_out[m * DM + c0];
            float4 h4 = *(const float4*)&hid[c0];
            acc += w4.x * h4.x + w4.y * h4.y + w4.z * h4.z + w4.w * h4.w;
        }
#pragma unroll
        for (int off = 8; off; off >>= 1) acc += __shfl_down(acc, off, 16);
        if (cc == 0) nh[m] = b_out[m] + acc;
    }
    __syncthreads();

    const int rv = rev[0];
    const int src = (rv == 0) ? pair[0] : pair[1];
    const int tar = (rv == 0) ? pair[1] : pair[0];
    float val;
    if (tok == src || tok == tar) {
        qrow[tid] = path_result[tid];
        __syncthreads();
        const float* x1 = (tok == src) ? nh : qrow;
        const float* x2 = (tok == src) ? qrow : nh;
        float acc = 0.f;
        for (int n = 0; n < 256; n += 4) {
            float4 w4 = *(const float4*)&W_agg[(size_t)tid * 512 + n];
            acc += w4.x * x1[n] + w4.y * x1[n + 1] + w4.z * x1[n + 2] + w4.w * x1[n + 3];
        }
        for (int n = 0; n < 256; n += 4) {
            float4 w4 = *(const float4*)&W_agg[(size_t)tid * 512 + 256 + n];
            acc += w4.x * x2[n] + w4.y * x2[n + 1] + w4.z * x2[n + 2] + w4.w * x2[n + 3];
        }
        val = acc;
    } else {
        val = nh[tid];
    }
    out[(size_t)tok * DM + tid] = val;
}

// -------------------- launcher --------------------
extern "C" void kernel_launch(void* const* d_in, const int* in_sizes, int n_in,
                              void* d_out, int out_size, void* d_ws, size_t ws_size,
                              hipStream_t stream) {
    const float* path    = (const float*)d_in[0];
    const float* q       = (const float*)d_in[2];
    const float* k       = (const float*)d_in[3];
    const float* v       = (const float*)d_in[4];
    const int*   edge_len  = (const int*)d_in[6];
    const int*   token_ids = (const int*)d_in[7];
    const int*   pair      = (const int*)d_in[8];
    const int*   rev       = (const int*)d_in[9];
    const float* W_qpair = (const float*)d_in[10];
    const float* W_pk    = (const float*)d_in[11];
    const float* W_pv    = (const float*)d_in[12];
    const float* W_q     = (const float*)d_in[13];
    const float* W_k     = (const float*)d_in[14];
    const float* W_v     = (const float*)d_in[15];
    const float* W_out   = (const float*)d_in[16];
    const float* b_out   = (const float*)d_in[17];
    const float* W_agg   = (const float*)d_in[18];
    float* out = (float*)d_out;

    char* base = (char*)d_ws;
    int*    starts      = (int*)(base + 0);              // 16 KB
    float*  path_result = (float*)(base + 16384);        // 1 KB
    float*  pv_ws       = (float*)(base + 17408);        // 64 KB
    float*  logits_ws   = (float*)(base + 82944);        // 1 KB
    ushortT* WQb        = (ushortT*)(base + 83968);      // 128 KB
    ushortT* WKTb       = (ushortT*)(base + 215040);     // 128 KB
    ushortT* WVb        = (ushortT*)(base + 346112);     // 128 KB
    ushortT* WOb        = (ushortT*)(base + 477184);     // 128 KB
    ushortT* tmat_u     = (ushortT*)(base + 608256);     // 32 MB
    const size_t NEED = 608256 + 33554432;

    if (ws_size >= NEED) {
        prep_kernel<<<dim3(3137), dim3(256), 0, stream>>>(
            q, out, edge_len, starts, path, pair, rev, W_qpair, W_pk, W_pv,
            pv_ws, logits_ws, W_q, W_k, W_v, W_out, WQb, WKTb, WVb, WOb);
        qhtmatC_kernel<<<dim3(257), dim3(256), 0, stream>>>(
            q, token_ids, WQb, WKTb, tmat_u, pv_ws, logits_ws, W_out, b_out,
            out + (size_t)SEN * DM, path_result);
        edge_kernel<<<dim3(NG), dim3(256), 0, stream>>>(k, v, edge_len, starts, tmat_u);
        hidnhagg_kernel<<<dim3(256), dim3(256), 0, stream>>>(
            tmat_u, WVb, WOb, b_out, token_ids, pair, rev, W_agg, path_result, out);
    } else {
        copy_kernel<<<dim3(2048), dim3(256), 0, stream>>>(q, out);
        scan_kernel<<<dim3(1), dim3(256), 0, stream>>>(edge_len, starts);
        pathB_kernel<<<dim3(PLEN), dim3(256), 0, stream>>>(path, q, pair, rev, W_qpair,
                                                           W_pk, W_pv, pv_ws, logits_ws);
        pathC_kernel<<<dim3(1), dim3(256), 0, stream>>>(pv_ws, logits_ws, W_out, b_out,
                                                        out + (size_t)SEN * DM, path_result);
        group_kernel<<<dim3(NG), dim3(256), 0, stream>>>(q, k, v, edge_len, token_ids, pair,
                                                         rev, W_q, W_k, W_v, W_out, b_out,
                                                         W_agg, starts, path_result, out);
    }
}